// Round 1
// baseline (285.213 us; speedup 1.0000x reference)
//
#include <hip/hip_runtime.h>
#include <stdint.h>

// Problem constants
#define BB 16
#define T1C 512
#define T2C 64
#define DC 768
#define HC 12
#define EC 64
#define SC 576          // T1+T2
#define QSCALE 0.35355339059327379f   // 64^-0.25

typedef __attribute__((ext_vector_type(8))) short bf16x8;   // 8 bf16 = 4 VGPRs
typedef __attribute__((ext_vector_type(4))) float f32x4;    // MFMA C/D

// ---------- bf16 helpers ----------
__device__ __forceinline__ uint16_t f2b(float f) {          // RNE
    union { float f; uint32_t i; } v; v.f = f;
    return (uint16_t)((v.i + 0x7fffu + ((v.i >> 16) & 1u)) >> 16);
}
__device__ __forceinline__ uint16_t f2bfast(float f) {      // round-half-up (cheap)
    union { float f; uint32_t i; } v; v.f = f;
    return (uint16_t)((v.i + 0x8000u) >> 16);
}
__device__ __forceinline__ uint32_t pk2(float a, float b) {
    return (uint32_t)f2b(a) | ((uint32_t)f2b(b) << 16);
}

// async global->LDS, 16B per lane; LDS dest = wave-uniform base + lane*16
__device__ __forceinline__ void gll16(const void* g, void* l) {
    __builtin_amdgcn_global_load_lds(
        (const __attribute__((address_space(1))) uint32_t*)(uintptr_t)g,
        (__attribute__((address_space(3))) uint32_t*)(uintptr_t)l, 16, 0, 0);
}

// ---------- mask layout detection (deterministic -> graph-safe) ----------
__global__ void detect(const uint32_t* __restrict__ mw, int* __restrict__ flags) {
    __shared__ int aW, aB, aL;
    if (threadIdx.x == 0) { aW = 0; aB = 0; aL = 0; }
    __syncthreads();
    int lW = 0, lB = 0, lL = 0;
    for (int i = threadIdx.x; i < 2304; i += 256) {
        uint32_t w = mw[i];
        if (w > 1u) lW = 1;
        if (((w) & 0xffu) > 1u || ((w >> 8) & 0xffu) > 1u ||
            ((w >> 16) & 0xffu) > 1u || ((w >> 24) & 0xffu) > 1u) lB = 1;
        if ((w & 0xffffu) > 1u) lL = 1;
    }
    if (lW) atomicOr(&aW, 1);
    if (lB) atomicOr(&aB, 1);
    if (lL) atomicOr(&aL, 1);
    __syncthreads();
    if (threadIdx.x == 0)
        flags[0] = (!aW) ? 0 : ((!aB) ? 1 : (aL ? 2 : 0));
}

// ---------- weight transpose + f32->bf16 ----------
// Wt[z][f][k] = W_z[k][f] bf16; z: 0..5 = W_f, 6..11 = W_i, 12 = Wu_v, 13 = Wu_l
__global__ __launch_bounds__(256) void wtrans(
    const float* __restrict__ Wf, const float* __restrict__ Wi,
    const float* __restrict__ Wuv, const float* __restrict__ Wul,
    uint16_t* __restrict__ Wt)
{
    __shared__ float tile[32][33];
    const int z = blockIdx.z;
    const float* src = (z < 6)  ? Wf + (size_t)z * DC * DC
                     : (z < 12) ? Wi + (size_t)(z - 6) * DC * DC
                     : (z == 12 ? Wuv : Wul);
    uint16_t* dst = Wt + (size_t)z * DC * DC;
    const int tx = threadIdx.x & 31, ty = threadIdx.x >> 5;
    const int k0 = blockIdx.x * 32, f0 = blockIdx.y * 32;
#pragma unroll
    for (int r = 0; r < 4; r++)
        tile[ty + r * 8][tx] = src[(size_t)(k0 + ty + r * 8) * DC + f0 + tx];
    __syncthreads();
#pragma unroll
    for (int r = 0; r < 4; r++)
        dst[(size_t)(f0 + ty + r * 8) * DC + k0 + tx] = f2b(tile[tx][ty + r * 8]);
}

// ---------- X f32 -> bf16 convert (plain row-major; staging swizzle is done
// at gemm_proj's global-source addressing, LDS dest stays linear) ----------
__global__ __launch_bounds__(256) void xcvt(
    const float* __restrict__ Xf, const float* __restrict__ Xi,
    uint16_t* __restrict__ Of, uint16_t* __restrict__ Oi)
{
    const int nf = BB * T1C * DC / 8;
    const int ni = BB * T2C * DC / 8;
    int t = blockIdx.x * 256 + threadIdx.x;
    const float* src; uint16_t* dst; int c;
    if (t < nf) { src = Xf; dst = Of; c = t; }
    else        { c = t - nf; if (c >= ni) return; src = Xi; dst = Oi; }
    const float* sp = src + (size_t)c * 8;
    float4 a = *(const float4*)sp;
    float4 b = *(const float4*)(sp + 4);
    uint4 o;
    o.x = pk2(a.x, a.y); o.y = pk2(a.z, a.w);
    o.z = pk2(b.x, b.y); o.w = pk2(b.z, b.w);
    *(uint4*)(dst + (size_t)c * 8) = o;
}

#define BSTR 76   // epilogue bounce stride (bf16 elems), conflict-free

// ---------- MFMA projection GEMM: 3-buffer deep pipeline, counted vmcnt ----------
// BM=256 x BN=128, BK=64, 512 threads = 8 waves (4m x 2n), wave tile 64x64.
// Tile t computed from buf[t%3]; tile t+2 staged (6 gll16/wave) into buf[(t+2)%3]
// whose reads finished a full tile ago -> no DMA-landing race by construction.
// vmcnt(6) once per K-tile (= tile t+2's loads in flight), vmcnt(0) only at t=10.
// LDS XOR swizzle: physical 16B chunk p = logical c ^ (row&7); applied on the
// global SOURCE address (gll16 dest must stay linear) and on the ds_read addr.
__global__ __launch_bounds__(512, 2) void gemm_proj_mfma(
    const uint16_t* __restrict__ Xbf, const uint16_t* __restrict__ Xbi,
    const uint16_t* __restrict__ Wt,
    const float* __restrict__ b_f, const float* __restrict__ b_i,
    uint16_t* __restrict__ Pf, uint16_t* __restrict__ Pi)
{
    __shared__ union {
        struct { uint16_t A[3][256 * 64]; uint16_t B[3][128 * 64]; } st; // 144 KB
        uint16_t bounce[8][16 * BSTR];                                   // epilogue
    } sm;

    const int tid = threadIdx.x;
    const int w = tid >> 6, l = tid & 63;
    const int lid = l & 15, qd = l >> 4;
    const bool isf = (blockIdx.x < 32);
    const int mx = isf ? blockIdx.x : blockIdx.x - 32;
    const int m0 = mx * 256;
    const int T  = isf ? T1C : T2C;
    const uint16_t* Xb = isf ? Xbf : Xbi;
    const float* bias  = isf ? b_f : b_i;
    uint16_t* P        = isf ? Pf : Pi;
    const int vmask    = isf ? 0x24 : 0x22;
    const int k6 = blockIdx.y / 6, nt = blockIdx.y % 6;
    const int n0 = nt * 128;
    const uint16_t* Bsrc = Wt + (size_t)((isf ? 0 : 6) + k6) * DC * DC;

    const int wm = w >> 1, wn = w & 1;

    // ---- staging source pointers (inverse-swizzled global addresses) ----
    // A tile: 2048 chunks of 16B; thread covers g = i*512+tid, i=0..3.
    // physical (row=g>>3, slot=g&7) receives logical col-chunk slot^(row&7).
    const uint16_t* aSrc[4];
#pragma unroll
    for (int i = 0; i < 4; ++i) {
        int g = i * 512 + tid, r = g >> 3, p = g & 7, cc = p ^ (r & 7);
        aSrc[i] = Xb + (size_t)(m0 + r) * DC + cc * 8;
    }
    const uint16_t* bSrc2[2];
#pragma unroll
    for (int i = 0; i < 2; ++i) {
        int g = i * 512 + tid, r = g >> 3, p = g & 7, cc = p ^ (r & 7);
        bSrc2[i] = Bsrc + (size_t)(n0 + r) * DC + cc * 8;
    }

    // ---- fragment LDS byte offsets (swizzled reads) ----
    // frag (kk,i): row = base + lid, logical chunk c = kk*4+qd,
    // byte = row*128 + (c ^ (lid&7))*16  (base multiple of 16 -> row&7 = lid&7)
    uint32_t aOff[2][4], bOff[2][4];
#pragma unroll
    for (int kk = 0; kk < 2; ++kk)
#pragma unroll
        for (int i = 0; i < 4; ++i) {
            int ra = wm * 64 + i * 16 + lid;
            int rb = wn * 64 + i * 16 + lid;
            uint32_t sl = (uint32_t)(((kk * 4 + qd) ^ (lid & 7)) * 16);
            aOff[kk][i] = (uint32_t)ra * 128 + sl;
            bOff[kk][i] = (uint32_t)rb * 128 + sl;
        }

#define STG_A(tk, bu, i) gll16(aSrc[i] + (tk) * 64, (uint16_t*)sm.st.A[bu] + (size_t)((i) * 512 + w * 64) * 8)
#define STG_B(tk, bu, i) gll16(bSrc2[i] + (tk) * 64, (uint16_t*)sm.st.B[bu] + (size_t)((i) * 512 + w * 64) * 8)
#define AFRAG(bu, kk, i) (*(const bf16x8*)((const char*)sm.st.A[bu] + aOff[kk][i]))
#define BFRAG(bu, kk, j) (*(const bf16x8*)((const char*)sm.st.B[bu] + bOff[kk][j]))

    // ---- prologue: stage tiles 0 and 1, wait tile 0 landed (vmcnt 6 = tile1) ----
    STG_A(0, 0, 0); STG_A(0, 0, 1); STG_A(0, 0, 2); STG_A(0, 0, 3);
    STG_B(0, 0, 0); STG_B(0, 0, 1);
    STG_A(1, 1, 0); STG_A(1, 1, 1); STG_A(1, 1, 2); STG_A(1, 1, 3);
    STG_B(1, 1, 0); STG_B(1, 1, 1);
    asm volatile("s_waitcnt vmcnt(6)" ::: "memory");
    __builtin_amdgcn_s_barrier();
    asm volatile("" ::: "memory");
    __builtin_amdgcn_sched_barrier(0);

    f32x4 acc[4][4] = {};

#pragma unroll
    for (int kt = 0; kt < 12; ++kt) {
        const int cb = kt % 3, sb = (kt + 2) % 3;

        // ============ phase 0 (kk = 0) ============
        if (kt < 10) { STG_A(kt + 2, sb, 0); STG_A(kt + 2, sb, 1); STG_B(kt + 2, sb, 0); }
        {
            bf16x8 a0[4], b0[4];
#pragma unroll
            for (int i = 0; i < 4; ++i) a0[i] = AFRAG(cb, 0, i);
#pragma unroll
            for (int j = 0; j < 4; ++j) b0[j] = BFRAG(cb, 0, j);
            __builtin_amdgcn_s_barrier();
            asm volatile("s_waitcnt lgkmcnt(0)" ::: "memory");
            __builtin_amdgcn_sched_barrier(0);
            __builtin_amdgcn_s_setprio(1);
#pragma unroll
            for (int i = 0; i < 4; ++i)
#pragma unroll
                for (int j = 0; j < 4; ++j)
                    acc[i][j] = __builtin_amdgcn_mfma_f32_16x16x32_bf16(a0[i], b0[j], acc[i][j], 0, 0, 0);
            __builtin_amdgcn_s_setprio(0);
            __builtin_amdgcn_sched_barrier(0);
            __builtin_amdgcn_s_barrier();
            asm volatile("" ::: "memory");
            __builtin_amdgcn_sched_barrier(0);
        }

        // ============ phase 1 (kk = 1) ============
        if (kt < 10) { STG_A(kt + 2, sb, 2); STG_A(kt + 2, sb, 3); STG_B(kt + 2, sb, 1); }
        {
            bf16x8 a1[4], b1[4];
#pragma unroll
            for (int i = 0; i < 4; ++i) a1[i] = AFRAG(cb, 1, i);
#pragma unroll
            for (int j = 0; j < 4; ++j) b1[j] = BFRAG(cb, 1, j);
            __builtin_amdgcn_s_barrier();
            asm volatile("s_waitcnt lgkmcnt(0)" ::: "memory");
            __builtin_amdgcn_sched_barrier(0);
            __builtin_amdgcn_s_setprio(1);
#pragma unroll
            for (int i = 0; i < 4; ++i)
#pragma unroll
                for (int j = 0; j < 4; ++j)
                    acc[i][j] = __builtin_amdgcn_mfma_f32_16x16x32_bf16(a1[i], b1[j], acc[i][j], 0, 0, 0);
            __builtin_amdgcn_s_setprio(0);
            __builtin_amdgcn_sched_barrier(0);
            // counted wait: ensure tile kt+1 fully landed before next tile's reads
            if (kt < 10)       { asm volatile("s_waitcnt vmcnt(6)" ::: "memory"); }
            else if (kt == 10) { asm volatile("s_waitcnt vmcnt(0)" ::: "memory"); }
            __builtin_amdgcn_s_barrier();
            asm volatile("" ::: "memory");
            __builtin_amdgcn_sched_barrier(0);
        }
    }
    __syncthreads();   // full drain before LDS reuse as bounce buffer

    // ---- epilogue (bounce through LDS for coalesced 16B stores) ----
    float bv[4];
#pragma unroll
    for (int j = 0; j < 4; ++j)
        bv[j] = bias[k6 * DC + n0 + wn * 64 + j * 16 + lid];

    uint16_t* reg = sm.bounce[w];
    const int mb = m0 + wm * 64;
    const int b = mb / T, tb = mb - b * T;     // 64-row wave tile never crosses b
    const int h = nt * 2 + wn;
    const int rrow = l >> 2;                   // readback row within pass
    const int rcol = (l & 3) * 16;             // readback col chunk

    if (!((vmask >> k6) & 1)) {
        // normal [t][e]: pass p = m-rows p*16..p*16+15 (i = p)
        uint16_t* dst0 = P + ((((size_t)k6 * BB + b) * HC + h) * T + tb + rrow) * EC + rcol;
#pragma unroll
        for (int p = 0; p < 4; p++) {
#pragma unroll
            for (int j = 0; j < 4; j++)
#pragma unroll
                for (int r = 0; r < 4; r++)
                    reg[(qd * 4 + r) * BSTR + j * 16 + lid] =
                        f2b((acc[p][j][r] + bv[j]) * QSCALE);
            uint4 d0 = *(const uint4*)&reg[rrow * BSTR + rcol];
            uint4 d1 = *(const uint4*)&reg[rrow * BSTR + rcol + 8];
            uint16_t* dst = dst0 + (size_t)p * 16 * EC;
            *(uint4*)dst = d0;
            *(uint4*)(dst + 8) = d1;
        }
    } else {
        // transposed [e][t]: pass p = e-rows p*16..p*16+15 (j = p)
        uint16_t* dst0 = P + (size_t)k6 * BB * HC * T * EC
                           + (((size_t)b * HC + h) * EC + rrow) * T + tb + rcol;
#pragma unroll
        for (int p = 0; p < 4; p++) {
#pragma unroll
            for (int i = 0; i < 4; i++) {
                uint32_t w0 = pk2((acc[i][p][0] + bv[p]) * QSCALE,
                                  (acc[i][p][1] + bv[p]) * QSCALE);
                uint32_t w1 = pk2((acc[i][p][2] + bv[p]) * QSCALE,
                                  (acc[i][p][3] + bv[p]) * QSCALE);
                *(uint2*)&reg[lid * BSTR + i * 16 + qd * 4] = make_uint2(w0, w1);
            }
            uint4 d0 = *(const uint4*)&reg[rrow * BSTR + rcol];
            uint4 d1 = *(const uint4*)&reg[rrow * BSTR + rcol + 8];
            uint16_t* dst = dst0 + (size_t)p * 16 * T;
            *(uint4*)dst = d0;
            *(uint4*)(dst + 8) = d1;
        }
    }
#undef STG_A
#undef STG_B
#undef AFRAG
#undef BFRAG
}

// ---------- MFMA output GEMM ----------
// A = attn output, PRE-SWIZZLED in frag order (written by attn) -> direct loads.
// Merged visual+language: blockIdx.x < 64 -> visual, else language.
__global__ __launch_bounds__(256, 3) void gemm_out_mfma(
    const uint16_t* __restrict__ Osv, const uint16_t* __restrict__ Osl,
    const uint16_t* __restrict__ Wt,
    const float* __restrict__ bu_v, const float* __restrict__ bu_l,
    float* __restrict__ out)
{
    __shared__ uint16_t Bs[128 * 32];
    const int tid = threadIdx.x;
    const int w = tid >> 6, l = tid & 63;
    const bool isv = (blockIdx.x < 64);
    const int mx = isv ? blockIdx.x : blockIdx.x - 64;
    const int m0 = mx * 128;
    const int rowoff = isv ? 0 : BB * T1C;
    const uint16_t* A = isv ? Osv : Osl;
    const uint16_t* Wtm = Wt + (size_t)(isv ? 12 : 13) * DC * DC;
    const float* bias = isv ? bu_v : bu_l;
    const int n0 = blockIdx.y * 128;
    const int lid = l & 15, qd = l >> 4;
    const int wm = w >> 1, wn = w & 1;
    const int br = l >> 2, bk = (l & 3) * 8;
    const int p0 = mx * 8 + wm * 4;

    f32x4 acc[4][4] = {};

    for (int kt = 0; kt < DC / 32; ++kt) {
        __syncthreads();
#pragma unroll
        for (int n = 0; n < 2; ++n) {
            int c = w * 2 + n;
            gll16(Wtm + (size_t)(n0 + c * 16 + br) * DC + kt * 32 + bk, &Bs[c * 512]);
        }
        bf16x8 af[4];
#pragma unroll
        for (int i = 0; i < 4; i++)
            af[i] = *(const bf16x8*)(A + ((size_t)((p0 + i) * 24 + kt) * 64 + l) * 8);
        __syncthreads();
        bf16x8 bf[4];
#pragma unroll
        for (int j = 0; j < 4; j++)
            bf[j] = *(const bf16x8*)&Bs[(wn * 64 + j * 16 + lid) * 32 + qd * 8];
#pragma unroll
        for (int i = 0; i < 4; i++)
#pragma unroll
            for (int j = 0; j < 4; j++)
                acc[i][j] = __builtin_amdgcn_mfma_f32_16x16x32_bf16(af[i], bf[j], acc[i][j], 0, 0, 0);
    }

    float bv[4];
#pragma unroll
    for (int j = 0; j < 4; j++)
        bv[j] = bias[n0 + wn * 64 + j * 16 + lid];
#pragma unroll
    for (int i = 0; i < 4; i++)
#pragma unroll
        for (int j = 0; j < 4; j++)
#pragma unroll
            for (int r = 0; r < 4; r++) {
                int m = m0 + wm * 64 + i * 16 + qd * 4 + r;
                int f = n0 + wn * 64 + j * 16 + lid;
                out[(size_t)(rowoff + m) * DC + f] = acc[i][j][r] + bv[j];
            }
}

// ---------- MFMA flash attention: LDS-staged K/V, no-max softmax ----------
// grid (192 bh, 9 tiles): 192%8==0 => all 9 tiles of one bh map to the SAME
// XCD (linear%8 = bh%8) for K/V L2 reuse. K staged [key][e] stride 72 via
// coalesced loads shared by all 4 waves; V^T staged [e][key]. P round-trips
// through wave-local LDS. O written pre-swizzled in gemm_out's A-frag order.
__global__ __launch_bounds__(256, 3) void attn_mfma(
    const uint16_t* __restrict__ Pf,
    const uint16_t* __restrict__ Pi,
    const void* __restrict__ maskp,
    const int* __restrict__ flags,
    uint16_t* __restrict__ Osv,        // swizzled visual O (M=8192)
    uint16_t* __restrict__ Osl)        // swizzled language O (M=1024)
{
    __shared__ uint16_t Klds[64 * 72];      // [key][e]
    __shared__ uint16_t Vlds[64 * 72];      // [e][key]
    __shared__ uint16_t Plds[4][16 * 72];   // per-wave P [q][key]
    __shared__ float    Ma[SC];
    __shared__ float    Lw[4][16];

    const int bh = blockIdx.x;
    const int tile = blockIdx.y;
    const int b = bh / HC, h = bh % HC;
    const int tid = threadIdx.x;
    const int w = tid >> 6, l = tid & 63;
    const int lid = l & 15, qd = l >> 4;

    const size_t SF = (size_t)BB * HC * T1C * EC;
    const size_t SI = (size_t)BB * HC * T2C * EC;

    const bool vis = (tile < 8);
    const uint16_t *Qa, *Qb, *K1, *K2, *V1, *V2;
    uint16_t* O; int Tq, q0;
    if (vis) { Qa = Pf + 1 * SF; Qb = Pf + 3 * SF; K1 = Pf;          K2 = Pi;
               V1 = Pf + 2 * SF; V2 = Pi + 1 * SI; O = Osv; Tq = T1C; q0 = tile * 64; }
    else     { Qa = Pi + 2 * SI; Qb = Pi + 3 * SI; K1 = Pf + 4 * SF; K2 = Pi + 4 * SI;
               V1 = Pf + 5 * SF; V2 = Pi + 5 * SI; O = Osl; Tq = T2C; q0 = 0; }

    {
        const int kind = flags[0];
        for (int i = tid; i < SC; i += 256) {
            int idx = b * SC + i;
            int mv;
            if (kind == 0)      mv = ((const uint32_t*)maskp)[idx] != 0u;
            else if (kind == 1) mv = ((const uint8_t*)maskp)[idx] != 0;
            else                mv = ((const uint16_t*)maskp)[idx] != 0;
            Ma[i] = mv ? -1e9f : 0.0f;
        }
    }

    const int q = q0 + w * 16 + lid;
    const uint16_t* Qrow = Qa + ((size_t)bh * Tq + q) * EC;
    bf16x8 qf0 = *(const bf16x8*)(Qrow + qd * 8);
    bf16x8 qf1 = *(const bf16x8*)(Qrow + 32 + qd * 8);

    f32x4 o[4];
#pragma unroll
    for (int ef = 0; ef < 4; ef++) { o[ef][0]=0.f; o[ef][1]=0.f; o[ef][2]=0.f; o[ef][3]=0.f; }
    float u[4] = {0.f, 0.f, 0.f, 0.f};

    const int skey = tid >> 2, se0 = (tid & 3) * 16;   // K stage (row, col chunk)
    const int ve = tid >> 2,  vc = tid & 3;            // V stage (e-row, key chunk)

    for (int c = 0; c < 9; ++c) {
        const uint16_t *Ksrc, *Vbase; int Tkv, kofs;
        if (c < 8) {
            Ksrc = K1 + ((size_t)bh * T1C + c * 64) * EC;
            Vbase = V1 + (size_t)bh * EC * T1C; Tkv = T1C; kofs = c * 64;
        } else {
            Ksrc = K2 + (size_t)bh * T2C * EC;
            Vbase = V2 + (size_t)bh * EC * T2C; Tkv = T2C; kofs = 0;
            const uint16_t* Qrow2 = Qb + ((size_t)bh * Tq + q) * EC;  // query switch
            qf0 = *(const bf16x8*)(Qrow2 + qd * 8);
            qf1 = *(const bf16x8*)(Qrow2 + 32 + qd * 8);
        }
        __syncthreads();   // prior chunk's K/V LDS reads complete (also covers Ma @c=0)
        *(uint4*)&Klds[skey * 72 + se0]     = *(const uint4*)(Ksrc + skey * EC + se0);
        *(uint4*)&Klds[skey * 72 + se0 + 8] = *(const uint4*)(Ksrc + skey * EC + se0 + 8);
#pragma unroll
        for (int g = 0; g < 2; g++) {
            int key0 = vc * 16 + g * 8;
            *(uint4*)&Vlds[ve * 72 + key0] =
                *(const uint4*)(Vbase + (size_t)ve * Tkv + kofs + key0);
        }
        __syncthreads();

        const int k0 = c * 64;
        // QK^T: D[q][key]
        f32x4 s[4];
#pragma unroll
        for (int sub = 0; sub < 4; sub++) {
            bf16x8 kf0 = *(const bf16x8*)&Klds[(sub * 16 + lid) * 72 + qd * 8];
            bf16x8 kf1 = *(const bf16x8*)&Klds[(sub * 16 + lid) * 72 + 32 + qd * 8];
            f32x4 z; z[0]=0.f; z[1]=0.f; z[2]=0.f; z[3]=0.f;
            z = __builtin_amdgcn_mfma_f32_16x16x32_bf16(qf0, kf0, z, 0, 0, 0);
            s[sub] = __builtin_amdgcn_mfma_f32_16x16x32_bf16(qf1, kf1, z, 0, 0, 0);
        }
        // p = exp(s + mask); accumulate row-sum; write P (C-layout -> [q][key])
#pragma unroll
        for (int sub = 0; sub < 4; sub++) {
            float mv = Ma[k0 + sub * 16 + lid];
#pragma unroll
            for (int r = 0; r < 4; r++) {
                float p = __expf(s[sub][r] + mv);
                u[r] += p;
                Plds[w][(qd * 4 + r) * 72 + sub * 16 + lid] = f2bfast(p);
            }
        }
        // PV as O^T = Vt * P^T (wave-local Plds round trip, no barrier)
#pragma unroll
        for (int half = 0; half < 2; half++) {
            bf16x8 pf = *(const bf16x8*)&Plds[w][lid * 72 + half * 32 + qd * 8];
#pragma unroll
            for (int ef = 0; ef < 4; ef++) {
                bf16x8 vf = *(const bf16x8*)&Vlds[(ef * 16 + lid) * 72 + half * 32 + qd * 8];
                o[ef] = __builtin_amdgcn_mfma_f32_16x16x32_bf16(vf, pf, o[ef], 0, 0, 0);
            }
        }
    }

    // one-time row-sum reduction across key-lanes (bits 0-3)
#pragma unroll
    for (int d = 1; d <= 8; d <<= 1)
#pragma unroll
        for (int r = 0; r < 4; r++)
            u[r] += __shfl_xor(u[r], d, 64);
    if (lid == 0) {
#pragma unroll
        for (int r = 0; r < 4; r++) Lw[w][qd * 4 + r] = u[r];
    }
    float rl = 1.f / Lw[w][lid];   // l for this lane's query (wave-local ordering)

    // O write in gemm_out's swizzled A-frag order:
    // m = b*Tq + q; panel p = m>>4 (wave-uniform), rlid = lid.
    // col = h*64 + e, e = ef*16 + qd*4 + r  ->  kt = h*2 + (ef>>1),
    // cq = (ef&1)*2 + (qd>>1), j = (qd&1)*4 + r  -> one 8B store per ef.
    const size_t p = ((size_t)b * Tq + q0 + w * 16) >> 4;
#pragma unroll
    for (int ef = 0; ef < 4; ef++) {
        uint32_t w0 = pk2(o[ef][0] * rl, o[ef][1] * rl);
        uint32_t w1 = pk2(o[ef][2] * rl, o[ef][3] * rl);
        size_t chunk = ((p * 24 + h * 2 + (ef >> 1)) * 4 + (ef & 1) * 2 + (qd >> 1)) * 16 + lid;
        *(uint2*)(O + chunk * 8 + (qd & 1) * 4) = make_uint2(w0, w1);
    }
}

// ---------- launch ----------
extern "C" void kernel_launch(void* const* d_in, const int* in_sizes, int n_in,
                              void* d_out, int out_size, void* d_ws, size_t ws_size,
                              hipStream_t stream)
{
    const float* feats = (const float*)d_in[0];
    const float* inps  = (const float*)d_in[1];
    const void*  maskp = d_in[2];
    const float* W_f   = (const float*)d_in[3];
    const float* b_f   = (const float*)d_in[4];
    const float* W_i   = (const float*)d_in[5];
    const float* b_i   = (const float*)d_in[6];
    const float* Wu_v  = (const float*)d_in[7];
    const float* bu_v  = (const float*)d_in[8];
    const float* Wu_l  = (const float*)d_in[9];
    const float* bu_l  = (const float*)d_in[10];

    const size_t MAT = (size_t)DC * DC;               // 589824
    const size_t PF_E = 6ull * BB * HC * T1C * EC;
    const size_t PI_E = 6ull * BB * HC * T2C * EC;
    uint16_t* Wt  = (uint16_t*)d_ws;
    uint16_t* Osv = Wt;                               // reuses dead Wt[0..11]
    uint16_t* Osl = Wt + (size_t)BB * T1C * HC * EC;
    uint16_t* Pf  = Wt + 14 * MAT;
    uint16_t* Pi  = Pf + PF_E;
    int* flags    = (int*)(Pi + PI_E);

    // Row-major bf16 X lives in d_out's first ~14 MB: d_out is only written by
    // the final gemm_out launch (stream-ordered after all Xb reads).
    uint16_t* Xbf = (uint16_t*)d_out;
    uint16_t* Xbi = Xbf + (size_t)BB * T1C * DC;

    detect<<<dim3(1), dim3(256), 0, stream>>>((const uint32_t*)maskp, flags);

    wtrans<<<dim3(24, 24, 14), dim3(256), 0, stream>>>(W_f, W_i, Wu_v, Wu_l, Wt);

    {
        int nchunks = (BB * T1C * DC + BB * T2C * DC) / 8;
        xcvt<<<dim3((nchunks + 255) / 256), dim3(256), 0, stream>>>(feats, inps, Xbf, Xbi);
    }

    gemm_proj_mfma<<<dim3(36, 36), dim3(512), 0, stream>>>(
        Xbf, Xbi, Wt, b_f, b_i, Pf, Pi);

    attn_mfma<<<dim3(BB * HC, 9), dim3(256), 0, stream>>>(
        Pf, Pi, maskp, flags, Osv, Osl);

    gemm_out_mfma<<<dim3(72, 6), dim3(256), 0, stream>>>(
        Osv, Osl, Wt, bu_v, bu_l, (float*)d_out);
}

// Round 2
// 280.596 us; speedup vs baseline: 1.0165x; 1.0165x over previous
//
#include <hip/hip_runtime.h>
#include <stdint.h>

// Problem constants
#define BB 16
#define T1C 512
#define T2C 64
#define DC 768
#define HC 12
#define EC 64
#define SC 576          // T1+T2
#define QSCALE 0.35355339059327379f   // 64^-0.25

typedef __attribute__((ext_vector_type(8))) short bf16x8;   // 8 bf16 = 4 VGPRs
typedef __attribute__((ext_vector_type(4))) float f32x4;    // MFMA C/D

// ---------- bf16 helpers ----------
__device__ __forceinline__ uint16_t f2b(float f) {          // RNE
    union { float f; uint32_t i; } v; v.f = f;
    return (uint16_t)((v.i + 0x7fffu + ((v.i >> 16) & 1u)) >> 16);
}
__device__ __forceinline__ uint16_t f2bfast(float f) {      // round-half-up (cheap)
    union { float f; uint32_t i; } v; v.f = f;
    return (uint16_t)((v.i + 0x8000u) >> 16);
}
__device__ __forceinline__ uint32_t pk2(float a, float b) {
    return (uint32_t)f2b(a) | ((uint32_t)f2b(b) << 16);
}

// async global->LDS, 16B per lane; LDS dest = wave-uniform base + lane*16
__device__ __forceinline__ void gll16(const void* g, void* l) {
    __builtin_amdgcn_global_load_lds(
        (const __attribute__((address_space(1))) uint32_t*)(uintptr_t)g,
        (__attribute__((address_space(3))) uint32_t*)(uintptr_t)l, 16, 0, 0);
}

// ---------- mask layout detection (deterministic -> graph-safe) ----------
__global__ void detect(const uint32_t* __restrict__ mw, int* __restrict__ flags) {
    __shared__ int aW, aB, aL;
    if (threadIdx.x == 0) { aW = 0; aB = 0; aL = 0; }
    __syncthreads();
    int lW = 0, lB = 0, lL = 0;
    for (int i = threadIdx.x; i < 2304; i += 256) {
        uint32_t w = mw[i];
        if (w > 1u) lW = 1;
        if (((w) & 0xffu) > 1u || ((w >> 8) & 0xffu) > 1u ||
            ((w >> 16) & 0xffu) > 1u || ((w >> 24) & 0xffu) > 1u) lB = 1;
        if ((w & 0xffffu) > 1u) lL = 1;
    }
    if (lW) atomicOr(&aW, 1);
    if (lB) atomicOr(&aB, 1);
    if (lL) atomicOr(&aL, 1);
    __syncthreads();
    if (threadIdx.x == 0)
        flags[0] = (!aW) ? 0 : ((!aB) ? 1 : (aL ? 2 : 0));
}

// ---------- weight transpose + f32->bf16 ----------
// Wt[z][f][k] = W_z[k][f] bf16; z: 0..5 = W_f, 6..11 = W_i, 12 = Wu_v, 13 = Wu_l
__global__ __launch_bounds__(256) void wtrans(
    const float* __restrict__ Wf, const float* __restrict__ Wi,
    const float* __restrict__ Wuv, const float* __restrict__ Wul,
    uint16_t* __restrict__ Wt)
{
    __shared__ float tile[32][33];
    const int z = blockIdx.z;
    const float* src = (z < 6)  ? Wf + (size_t)z * DC * DC
                     : (z < 12) ? Wi + (size_t)(z - 6) * DC * DC
                     : (z == 12 ? Wuv : Wul);
    uint16_t* dst = Wt + (size_t)z * DC * DC;
    const int tx = threadIdx.x & 31, ty = threadIdx.x >> 5;
    const int k0 = blockIdx.x * 32, f0 = blockIdx.y * 32;
#pragma unroll
    for (int r = 0; r < 4; r++)
        tile[ty + r * 8][tx] = src[(size_t)(k0 + ty + r * 8) * DC + f0 + tx];
    __syncthreads();
#pragma unroll
    for (int r = 0; r < 4; r++)
        dst[(size_t)(f0 + ty + r * 8) * DC + k0 + tx] = f2b(tile[tx][ty + r * 8]);
}

// ---------- X f32 -> bf16 swizzle prepass (MFMA A-fragment order) ----------
// chunk cc (8 elems): cc = ((p*24 + kt)*4 + qd)*16 + rlid
// holds X[p*16+rlid][kt*32 + qd*8 .. +7]. A frag load for (panel p, kt) is then
// 64 lanes x contiguous 16B = one coalesced 1KB burst.
__global__ __launch_bounds__(256) void xswz(
    const float* __restrict__ Xf, const float* __restrict__ Xi,
    uint16_t* __restrict__ Of, uint16_t* __restrict__ Oi)
{
    const int nf = BB * T1C * DC / 8;
    const int ni = BB * T2C * DC / 8;
    int t = blockIdx.x * 256 + threadIdx.x;
    const float* src; uint16_t* dst; int cc;
    if (t < nf) { src = Xf; dst = Of; cc = t; }
    else        { cc = t - nf; if (cc >= ni) return; src = Xi; dst = Oi; }
    int rlid = cc & 15;
    int t2 = cc >> 4;
    int qd = t2 & 3;
    int t3 = t2 >> 2;
    int kt = t3 % 24;
    int p  = t3 / 24;
    const float* sp = src + (size_t)(p * 16 + rlid) * DC + kt * 32 + qd * 8;
    float4 a = *(const float4*)sp;
    float4 b = *(const float4*)(sp + 4);
    uint4 o;
    o.x = pk2(a.x, a.y); o.y = pk2(a.z, a.w);
    o.z = pk2(b.x, b.y); o.w = pk2(b.z, b.w);
    *(uint4*)(dst + (size_t)cc * 8) = o;
}

#define BSTR 76   // epilogue bounce stride (bf16 elems), conflict-free

// ---------- MFMA projection GEMM ----------
// Baseline structure (128x128, 4 waves, 3 blocks/CU, grid (72,36): x%8 XCD
// locality for A re-reads) with a restructured staging schedule:
//  * BK=64 triple-buffered B in LDS (48 KB), XOR-swizzled (both-sides, so
//    gll16 dest stays linear: inverse-swizzled GLOBAL source + swizzled read).
//  * A-frags stay direct-global from the xswz'd layout (1KB coalesced bursts).
//  * Per tile t: issue A(t) loads, THEN stage(t+2) (newer in vmcnt order, so
//    A-consumption waits drain stage(t+1) -- issued last tile, strictly older
//    across the sched_barrier fence -- but NOT stage(t+2)).
//  * One raw s_barrier per tile, no waitcnt: stage(t+1)'s landing is already
//    per-wave-confirmed by this tile's A-frag waits; barrier publishes it.
// 12 barriers total (vs 48) and staging always has ~2 tiles in flight.
__global__ __launch_bounds__(256, 3) void gemm_proj_mfma(
    const uint16_t* __restrict__ Xsf, const uint16_t* __restrict__ Xsi,
    const uint16_t* __restrict__ Wt,
    const float* __restrict__ b_f, const float* __restrict__ b_i,
    uint16_t* __restrict__ Pf, uint16_t* __restrict__ Pi)
{
    __shared__ union {
        uint16_t B[3][128 * 64];              // 48 KB triple-buffered B (BK=64)
        uint16_t bounce[4][16 * BSTR];        // epilogue
    } sm;
    const int tid = threadIdx.x;
    const int w = tid >> 6, l = tid & 63;
    const bool isf = (blockIdx.x < 64);
    const int mx = isf ? blockIdx.x : blockIdx.x - 64;
    const int m0 = mx * 128;
    const int T  = isf ? T1C : T2C;
    const uint16_t* Xs = isf ? Xsf : Xsi;
    const float* bias  = isf ? b_f : b_i;
    uint16_t* P        = isf ? Pf : Pi;
    const int vmask    = isf ? 0x24 : 0x22;
    const int k6 = blockIdx.y / 6, nt = blockIdx.y % 6;
    const int n0 = nt * 128;
    const uint16_t* Bsrc = Wt + (size_t)((isf ? 0 : 6) + k6) * DC * DC;

    const int lid = l & 15, qd = l >> 4;
    const int wm = w >> 1, wn = w & 1;
    const int p0 = mx * 8 + wm * 4;           // A panel base for this wave

    // ---- staging: wave w, slot i covers LDS chunks [(i*4+w)*64, +64) ----
    // physical chunk pc -> row = pc>>3, phys slot = pc&7,
    // logical col-chunk = slot ^ (row&7)  (inverse-swizzled global source).
    const int r8 = l >> 3;                    // 0..7
    const int scol = (l & 7) ^ r8;            // logical chunk for this lane
    const uint16_t* bsrc[4];
    uint32_t bdst[4];
#pragma unroll
    for (int i = 0; i < 4; ++i) {
        bsrc[i] = Bsrc + (size_t)(n0 + (i * 4 + w) * 8 + r8) * DC + scol * 8;
        bdst[i] = (uint32_t)(i * 4 + w) * 512;        // elem offset in buffer
    }
    // ---- B-frag read offsets (swizzled): row*64 + ((kk*4+qd)^(lid&7))*8 ----
    uint32_t boff[2][4];
#pragma unroll
    for (int kk = 0; kk < 2; ++kk)
#pragma unroll
        for (int j = 0; j < 4; ++j) {
            int row = wn * 64 + j * 16 + lid;
            boff[kk][j] = (uint32_t)row * 64 + (uint32_t)((((kk * 4 + qd) ^ (lid & 7))) * 8);
        }

    f32x4 acc[4][4] = {};

    // ---- prologue: stage tiles 0 and 1; wait tile 0 (tile 1's 4 stay out) ----
#pragma unroll
    for (int i = 0; i < 4; ++i) gll16(bsrc[i],      &sm.B[0][bdst[i]]);
#pragma unroll
    for (int i = 0; i < 4; ++i) gll16(bsrc[i] + 64, &sm.B[1][bdst[i]]);
    asm volatile("s_waitcnt vmcnt(4)" ::: "memory");
    __builtin_amdgcn_s_barrier();
    __builtin_amdgcn_sched_barrier(0);

#pragma unroll
    for (int ktt = 0; ktt < 12; ++ktt) {
        const int cb = ktt % 3;
        // A-frags for this tile (8 x 1KB coalesced global bursts)
        bf16x8 af[2][4];
#pragma unroll
        for (int kk = 0; kk < 2; ++kk)
#pragma unroll
            for (int i = 0; i < 4; ++i)
                af[kk][i] = *(const bf16x8*)(Xs +
                    ((size_t)((p0 + i) * 24 + ktt * 2 + kk) * 64 + l) * 8);
        // deep prefetch: stage tile ktt+2 (issued AFTER A -> survives A-waits)
        if (ktt < 10) {
            const int sb = (ktt + 2) % 3;
#pragma unroll
            for (int i = 0; i < 4; ++i)
                gll16(bsrc[i] + (ktt + 2) * 64, &sm.B[sb][bdst[i]]);
        }
        // B-frags + MFMA
#pragma unroll
        for (int kk = 0; kk < 2; ++kk) {
            bf16x8 bq[4];
#pragma unroll
            for (int j = 0; j < 4; ++j)
                bq[j] = *(const bf16x8*)&sm.B[cb][boff[kk][j]];
#pragma unroll
            for (int i = 0; i < 4; ++i)
#pragma unroll
                for (int j = 0; j < 4; ++j)
                    acc[i][j] = __builtin_amdgcn_mfma_f32_16x16x32_bf16(
                        af[kk][i], bq[j], acc[i][j], 0, 0, 0);
        }
        // tile boundary: publish stage(ktt+1); no drain needed.
        __builtin_amdgcn_sched_barrier(0);
        __builtin_amdgcn_s_barrier();
        __builtin_amdgcn_sched_barrier(0);
    }
    __syncthreads();   // full drain before LDS reuse as bounce buffer

    // ---- epilogue (bounce through LDS for coalesced 16B stores) ----
    float bv[4];
#pragma unroll
    for (int j = 0; j < 4; j++)
        bv[j] = bias[k6 * DC + n0 + wn * 64 + j * 16 + lid];

    uint16_t* reg = sm.bounce[w];
    const int mb = m0 + wm * 64;
    const int b = mb / T, tb = mb - b * T;     // 64-row wave tile never crosses b
    const int h = nt * 2 + wn;
    const int rrow = l >> 2;                   // readback row within pass
    const int rcol = (l & 3) * 16;             // readback col chunk

    if (!((vmask >> k6) & 1)) {
        // normal [t][e]: pass p = m-rows p*16..p*16+15 (i = p)
        uint16_t* dst0 = P + ((((size_t)k6 * BB + b) * HC + h) * T + tb + rrow) * EC + rcol;
#pragma unroll
        for (int p = 0; p < 4; p++) {
#pragma unroll
            for (int j = 0; j < 4; j++)
#pragma unroll
                for (int r = 0; r < 4; r++)
                    reg[(qd * 4 + r) * BSTR + j * 16 + lid] =
                        f2b((acc[p][j][r] + bv[j]) * QSCALE);
            uint4 d0 = *(const uint4*)&reg[rrow * BSTR + rcol];
            uint4 d1 = *(const uint4*)&reg[rrow * BSTR + rcol + 8];
            uint16_t* dst = dst0 + (size_t)p * 16 * EC;
            *(uint4*)dst = d0;
            *(uint4*)(dst + 8) = d1;
        }
    } else {
        // transposed [e][t]: pass p = e-rows p*16..p*16+15 (j = p)
        uint16_t* dst0 = P + (size_t)k6 * BB * HC * T * EC
                           + (((size_t)b * HC + h) * EC + rrow) * T + tb + rcol;
#pragma unroll
        for (int p = 0; p < 4; p++) {
#pragma unroll
            for (int i = 0; i < 4; i++) {
                uint32_t w0 = pk2((acc[i][p][0] + bv[p]) * QSCALE,
                                  (acc[i][p][1] + bv[p]) * QSCALE);
                uint32_t w1 = pk2((acc[i][p][2] + bv[p]) * QSCALE,
                                  (acc[i][p][3] + bv[p]) * QSCALE);
                *(uint2*)&reg[lid * BSTR + i * 16 + qd * 4] = make_uint2(w0, w1);
            }
            uint4 d0 = *(const uint4*)&reg[rrow * BSTR + rcol];
            uint4 d1 = *(const uint4*)&reg[rrow * BSTR + rcol + 8];
            uint16_t* dst = dst0 + (size_t)p * 16 * T;
            *(uint4*)dst = d0;
            *(uint4*)(dst + 8) = d1;
        }
    }
}

// ---------- MFMA output GEMM ----------
// A = attn output, PRE-SWIZZLED in frag order (written by attn) -> direct loads.
// Merged visual+language: blockIdx.x < 64 -> visual, else language.
__global__ __launch_bounds__(256, 3) void gemm_out_mfma(
    const uint16_t* __restrict__ Osv, const uint16_t* __restrict__ Osl,
    const uint16_t* __restrict__ Wt,
    const float* __restrict__ bu_v, const float* __restrict__ bu_l,
    float* __restrict__ out)
{
    __shared__ uint16_t Bs[128 * 32];
    const int tid = threadIdx.x;
    const int w = tid >> 6, l = tid & 63;
    const bool isv = (blockIdx.x < 64);
    const int mx = isv ? blockIdx.x : blockIdx.x - 64;
    const int m0 = mx * 128;
    const int rowoff = isv ? 0 : BB * T1C;
    const uint16_t* A = isv ? Osv : Osl;
    const uint16_t* Wtm = Wt + (size_t)(isv ? 12 : 13) * DC * DC;
    const float* bias = isv ? bu_v : bu_l;
    const int n0 = blockIdx.y * 128;
    const int lid = l & 15, qd = l >> 4;
    const int wm = w >> 1, wn = w & 1;
    const int br = l >> 2, bk = (l & 3) * 8;
    const int p0 = mx * 8 + wm * 4;

    f32x4 acc[4][4] = {};

    for (int kt = 0; kt < DC / 32; ++kt) {
        __syncthreads();
#pragma unroll
        for (int n = 0; n < 2; ++n) {
            int c = w * 2 + n;
            gll16(Wtm + (size_t)(n0 + c * 16 + br) * DC + kt * 32 + bk, &Bs[c * 512]);
        }
        bf16x8 af[4];
#pragma unroll
        for (int i = 0; i < 4; i++)
            af[i] = *(const bf16x8*)(A + ((size_t)((p0 + i) * 24 + kt) * 64 + l) * 8);
        __syncthreads();
        bf16x8 bf[4];
#pragma unroll
        for (int j = 0; j < 4; j++)
            bf[j] = *(const bf16x8*)&Bs[(wn * 64 + j * 16 + lid) * 32 + qd * 8];
#pragma unroll
        for (int i = 0; i < 4; i++)
#pragma unroll
            for (int j = 0; j < 4; j++)
                acc[i][j] = __builtin_amdgcn_mfma_f32_16x16x32_bf16(af[i], bf[j], acc[i][j], 0, 0, 0);
    }

    float bv[4];
#pragma unroll
    for (int j = 0; j < 4; j++)
        bv[j] = bias[n0 + wn * 64 + j * 16 + lid];
#pragma unroll
    for (int i = 0; i < 4; i++)
#pragma unroll
        for (int j = 0; j < 4; j++)
#pragma unroll
            for (int r = 0; r < 4; r++) {
                int m = m0 + wm * 64 + i * 16 + qd * 4 + r;
                int f = n0 + wn * 64 + j * 16 + lid;
                out[(size_t)(rowoff + m) * DC + f] = acc[i][j][r] + bv[j];
            }
}

// ---------- MFMA flash attention: LDS-staged K/V, no-max softmax ----------
// grid (192 bh, 9 tiles): 192%8==0 => all 9 tiles of one bh map to the SAME
// XCD (linear%8 = bh%8) for K/V L2 reuse. K staged [key][e] stride 72 via
// coalesced loads shared by all 4 waves; V^T staged [e][key]. P round-trips
// through wave-local LDS. O written pre-swizzled in gemm_out's A-frag order.
__global__ __launch_bounds__(256, 3) void attn_mfma(
    const uint16_t* __restrict__ Pf,
    const uint16_t* __restrict__ Pi,
    const void* __restrict__ maskp,
    const int* __restrict__ flags,
    uint16_t* __restrict__ Osv,        // swizzled visual O (M=8192)
    uint16_t* __restrict__ Osl)        // swizzled language O (M=1024)
{
    __shared__ uint16_t Klds[64 * 72];      // [key][e]
    __shared__ uint16_t Vlds[64 * 72];      // [e][key]
    __shared__ uint16_t Plds[4][16 * 72];   // per-wave P [q][key]
    __shared__ float    Ma[SC];
    __shared__ float    Lw[4][16];

    const int bh = blockIdx.x;
    const int tile = blockIdx.y;
    const int b = bh / HC, h = bh % HC;
    const int tid = threadIdx.x;
    const int w = tid >> 6, l = tid & 63;
    const int lid = l & 15, qd = l >> 4;

    const size_t SF = (size_t)BB * HC * T1C * EC;
    const size_t SI = (size_t)BB * HC * T2C * EC;

    const bool vis = (tile < 8);
    const uint16_t *Qa, *Qb, *K1, *K2, *V1, *V2;
    uint16_t* O; int Tq, q0;
    if (vis) { Qa = Pf + 1 * SF; Qb = Pf + 3 * SF; K1 = Pf;          K2 = Pi;
               V1 = Pf + 2 * SF; V2 = Pi + 1 * SI; O = Osv; Tq = T1C; q0 = tile * 64; }
    else     { Qa = Pi + 2 * SI; Qb = Pi + 3 * SI; K1 = Pf + 4 * SF; K2 = Pi + 4 * SI;
               V1 = Pf + 5 * SF; V2 = Pi + 5 * SI; O = Osl; Tq = T2C; q0 = 0; }

    {
        const int kind = flags[0];
        for (int i = tid; i < SC; i += 256) {
            int idx = b * SC + i;
            int mv;
            if (kind == 0)      mv = ((const uint32_t*)maskp)[idx] != 0u;
            else if (kind == 1) mv = ((const uint8_t*)maskp)[idx] != 0;
            else                mv = ((const uint16_t*)maskp)[idx] != 0;
            Ma[i] = mv ? -1e9f : 0.0f;
        }
    }

    const int q = q0 + w * 16 + lid;
    const uint16_t* Qrow = Qa + ((size_t)bh * Tq + q) * EC;
    bf16x8 qf0 = *(const bf16x8*)(Qrow + qd * 8);
    bf16x8 qf1 = *(const bf16x8*)(Qrow + 32 + qd * 8);

    f32x4 o[4];
#pragma unroll
    for (int ef = 0; ef < 4; ef++) { o[ef][0]=0.f; o[ef][1]=0.f; o[ef][2]=0.f; o[ef][3]=0.f; }
    float u[4] = {0.f, 0.f, 0.f, 0.f};

    const int skey = tid >> 2, se0 = (tid & 3) * 16;   // K stage (row, col chunk)
    const int ve = tid >> 2,  vc = tid & 3;            // V stage (e-row, key chunk)

    for (int c = 0; c < 9; ++c) {
        const uint16_t *Ksrc, *Vbase; int Tkv, kofs;
        if (c < 8) {
            Ksrc = K1 + ((size_t)bh * T1C + c * 64) * EC;
            Vbase = V1 + (size_t)bh * EC * T1C; Tkv = T1C; kofs = c * 64;
        } else {
            Ksrc = K2 + (size_t)bh * T2C * EC;
            Vbase = V2 + (size_t)bh * EC * T2C; Tkv = T2C; kofs = 0;
            const uint16_t* Qrow2 = Qb + ((size_t)bh * Tq + q) * EC;  // query switch
            qf0 = *(const bf16x8*)(Qrow2 + qd * 8);
            qf1 = *(const bf16x8*)(Qrow2 + 32 + qd * 8);
        }
        __syncthreads();   // prior chunk's K/V LDS reads complete (also covers Ma @c=0)
        *(uint4*)&Klds[skey * 72 + se0]     = *(const uint4*)(Ksrc + skey * EC + se0);
        *(uint4*)&Klds[skey * 72 + se0 + 8] = *(const uint4*)(Ksrc + skey * EC + se0 + 8);
#pragma unroll
        for (int g = 0; g < 2; g++) {
            int key0 = vc * 16 + g * 8;
            *(uint4*)&Vlds[ve * 72 + key0] =
                *(const uint4*)(Vbase + (size_t)ve * Tkv + kofs + key0);
        }
        __syncthreads();

        const int k0 = c * 64;
        // QK^T: D[q][key]
        f32x4 s[4];
#pragma unroll
        for (int sub = 0; sub < 4; sub++) {
            bf16x8 kf0 = *(const bf16x8*)&Klds[(sub * 16 + lid) * 72 + qd * 8];
            bf16x8 kf1 = *(const bf16x8*)&Klds[(sub * 16 + lid) * 72 + 32 + qd * 8];
            f32x4 z; z[0]=0.f; z[1]=0.f; z[2]=0.f; z[3]=0.f;
            z = __builtin_amdgcn_mfma_f32_16x16x32_bf16(qf0, kf0, z, 0, 0, 0);
            s[sub] = __builtin_amdgcn_mfma_f32_16x16x32_bf16(qf1, kf1, z, 0, 0, 0);
        }
        // p = exp(s + mask); accumulate row-sum; write P (C-layout -> [q][key])
#pragma unroll
        for (int sub = 0; sub < 4; sub++) {
            float mv = Ma[k0 + sub * 16 + lid];
#pragma unroll
            for (int r = 0; r < 4; r++) {
                float p = __expf(s[sub][r] + mv);
                u[r] += p;
                Plds[w][(qd * 4 + r) * 72 + sub * 16 + lid] = f2bfast(p);
            }
        }
        // PV as O^T = Vt * P^T (wave-local Plds round trip, no barrier)
#pragma unroll
        for (int half = 0; half < 2; half++) {
            bf16x8 pf = *(const bf16x8*)&Plds[w][lid * 72 + half * 32 + qd * 8];
#pragma unroll
            for (int ef = 0; ef < 4; ef++) {
                bf16x8 vf = *(const bf16x8*)&Vlds[(ef * 16 + lid) * 72 + half * 32 + qd * 8];
                o[ef] = __builtin_amdgcn_mfma_f32_16x16x32_bf16(vf, pf, o[ef], 0, 0, 0);
            }
        }
    }

    // one-time row-sum reduction across key-lanes (bits 0-3)
#pragma unroll
    for (int d = 1; d <= 8; d <<= 1)
#pragma unroll
        for (int r = 0; r < 4; r++)
            u[r] += __shfl_xor(u[r], d, 64);
    if (lid == 0) {
#pragma unroll
        for (int r = 0; r < 4; r++) Lw[w][qd * 4 + r] = u[r];
    }
    float rl = 1.f / Lw[w][lid];   // l for this lane's query (wave-local ordering)

    // O write in gemm_out's swizzled A-frag order:
    // m = b*Tq + q; panel p = m>>4 (wave-uniform), rlid = lid.
    // col = h*64 + e, e = ef*16 + qd*4 + r  ->  kt = h*2 + (ef>>1),
    // cq = (ef&1)*2 + (qd>>1), j = (qd&1)*4 + r  -> one 8B store per ef.
    const size_t p = ((size_t)b * Tq + q0 + w * 16) >> 4;
#pragma unroll
    for (int ef = 0; ef < 4; ef++) {
        uint32_t w0 = pk2(o[ef][0] * rl, o[ef][1] * rl);
        uint32_t w1 = pk2(o[ef][2] * rl, o[ef][3] * rl);
        size_t chunk = ((p * 24 + h * 2 + (ef >> 1)) * 4 + (ef & 1) * 2 + (qd >> 1)) * 16 + lid;
        *(uint2*)(O + chunk * 8 + (qd & 1) * 4) = make_uint2(w0, w1);
    }
}

// ---------- launch ----------
extern "C" void kernel_launch(void* const* d_in, const int* in_sizes, int n_in,
                              void* d_out, int out_size, void* d_ws, size_t ws_size,
                              hipStream_t stream)
{
    const float* feats = (const float*)d_in[0];
    const float* inps  = (const float*)d_in[1];
    const void*  maskp = d_in[2];
    const float* W_f   = (const float*)d_in[3];
    const float* b_f   = (const float*)d_in[4];
    const float* W_i   = (const float*)d_in[5];
    const float* b_i   = (const float*)d_in[6];
    const float* Wu_v  = (const float*)d_in[7];
    const float* bu_v  = (const float*)d_in[8];
    const float* Wu_l  = (const float*)d_in[9];
    const float* bu_l  = (const float*)d_in[10];

    const size_t MAT = (size_t)DC * DC;               // 589824
    const size_t PF_E = 6ull * BB * HC * T1C * EC;
    const size_t PI_E = 6ull * BB * HC * T2C * EC;
    uint16_t* Wt  = (uint16_t*)d_ws;
    uint16_t* Osv = Wt;                               // reuses dead Wt[0..11]
    uint16_t* Osl = Wt + (size_t)BB * T1C * HC * EC;
    uint16_t* Pf  = Wt + 14 * MAT;
    uint16_t* Pi  = Pf + PF_E;
    int* flags    = (int*)(Pi + PI_E);

    // Swizzled bf16 X lives in d_out's first ~21 MB: d_out is only written by
    // the final gemm_out launch (stream-ordered after all Xs reads).
    uint16_t* Xsf = (uint16_t*)d_out;
    uint16_t* Xsi = Xsf + (size_t)BB * T1C * DC;

    detect<<<dim3(1), dim3(256), 0, stream>>>((const uint32_t*)maskp, flags);

    wtrans<<<dim3(24, 24, 14), dim3(256), 0, stream>>>(W_f, W_i, Wu_v, Wu_l, Wt);

    {
        int nchunks = (BB * T1C * DC + BB * T2C * DC) / 8;
        xswz<<<dim3((nchunks + 255) / 256), dim3(256), 0, stream>>>(feats, inps, Xsf, Xsi);
    }

    gemm_proj_mfma<<<dim3(72, 36), dim3(256), 0, stream>>>(
        Xsf, Xsi, Wt, b_f, b_i, Pf, Pi);

    attn_mfma<<<dim3(BB * HC, 9), dim3(256), 0, stream>>>(
        Pf, Pi, maskp, flags, Osv, Osl);

    gemm_out_mfma<<<dim3(72, 6), dim3(256), 0, stream>>>(
        Osv, Osl, Wt, bu_v, bu_l, (float*)d_out);
}

// Round 3
// 270.630 us; speedup vs baseline: 1.0539x; 1.0368x over previous
//
#include <hip/hip_runtime.h>
#include <stdint.h>

// Problem constants
#define BB 16
#define T1C 512
#define T2C 64
#define DC 768
#define HC 12
#define EC 64
#define SC 576          // T1+T2
#define QSCALE 0.35355339059327379f   // 64^-0.25

typedef __attribute__((ext_vector_type(8))) short bf16x8;   // 8 bf16 = 4 VGPRs
typedef __attribute__((ext_vector_type(4))) float f32x4;    // MFMA C/D

// ---------- bf16 helpers ----------
__device__ __forceinline__ uint16_t f2b(float f) {          // RNE
    union { float f; uint32_t i; } v; v.f = f;
    return (uint16_t)((v.i + 0x7fffu + ((v.i >> 16) & 1u)) >> 16);
}
__device__ __forceinline__ uint16_t f2bfast(float f) {      // round-half-up (cheap)
    union { float f; uint32_t i; } v; v.f = f;
    return (uint16_t)((v.i + 0x8000u) >> 16);
}
__device__ __forceinline__ uint32_t pk2(float a, float b) {
    return (uint32_t)f2b(a) | ((uint32_t)f2b(b) << 16);
}

// async global->LDS, 16B per lane; LDS dest = wave-uniform base + lane*16
__device__ __forceinline__ void gll16(const void* g, void* l) {
    __builtin_amdgcn_global_load_lds(
        (const __attribute__((address_space(1))) uint32_t*)(uintptr_t)g,
        (__attribute__((address_space(3))) uint32_t*)(uintptr_t)l, 16, 0, 0);
}

// ---------- mask layout detection (deterministic -> graph-safe) ----------
__global__ void detect(const uint32_t* __restrict__ mw, int* __restrict__ flags) {
    __shared__ int aW, aB, aL;
    if (threadIdx.x == 0) { aW = 0; aB = 0; aL = 0; }
    __syncthreads();
    int lW = 0, lB = 0, lL = 0;
    for (int i = threadIdx.x; i < 2304; i += 256) {
        uint32_t w = mw[i];
        if (w > 1u) lW = 1;
        if (((w) & 0xffu) > 1u || ((w >> 8) & 0xffu) > 1u ||
            ((w >> 16) & 0xffu) > 1u || ((w >> 24) & 0xffu) > 1u) lB = 1;
        if ((w & 0xffffu) > 1u) lL = 1;
    }
    if (lW) atomicOr(&aW, 1);
    if (lB) atomicOr(&aB, 1);
    if (lL) atomicOr(&aL, 1);
    __syncthreads();
    if (threadIdx.x == 0)
        flags[0] = (!aW) ? 0 : ((!aB) ? 1 : (aL ? 2 : 0));
}

// ---------- weight transpose + f32->bf16 ----------
// Wt[z][f][k] = W_z[k][f] bf16; z: 0..5 = W_f, 6..11 = W_i, 12 = Wu_v, 13 = Wu_l
__global__ __launch_bounds__(256) void wtrans(
    const float* __restrict__ Wf, const float* __restrict__ Wi,
    const float* __restrict__ Wuv, const float* __restrict__ Wul,
    uint16_t* __restrict__ Wt)
{
    __shared__ float tile[32][33];
    const int z = blockIdx.z;
    const float* src = (z < 6)  ? Wf + (size_t)z * DC * DC
                     : (z < 12) ? Wi + (size_t)(z - 6) * DC * DC
                     : (z == 12 ? Wuv : Wul);
    uint16_t* dst = Wt + (size_t)z * DC * DC;
    const int tx = threadIdx.x & 31, ty = threadIdx.x >> 5;
    const int k0 = blockIdx.x * 32, f0 = blockIdx.y * 32;
#pragma unroll
    for (int r = 0; r < 4; r++)
        tile[ty + r * 8][tx] = src[(size_t)(k0 + ty + r * 8) * DC + f0 + tx];
    __syncthreads();
#pragma unroll
    for (int r = 0; r < 4; r++)
        dst[(size_t)(f0 + ty + r * 8) * DC + k0 + tx] = f2b(tile[tx][ty + r * 8]);
}

// ---------- X f32 -> bf16 swizzle prepass (MFMA A-fragment order) ----------
// chunk cc (8 elems): cc = ((p*24 + kt)*4 + qd)*16 + rlid
// holds X[p*16+rlid][kt*32 + qd*8 .. +7]. A frag load for (panel p, kt) is then
// 64 lanes x contiguous 16B = one coalesced 1KB burst.
__global__ __launch_bounds__(256) void xswz(
    const float* __restrict__ Xf, const float* __restrict__ Xi,
    uint16_t* __restrict__ Of, uint16_t* __restrict__ Oi)
{
    const int nf = BB * T1C * DC / 8;
    const int ni = BB * T2C * DC / 8;
    int t = blockIdx.x * 256 + threadIdx.x;
    const float* src; uint16_t* dst; int cc;
    if (t < nf) { src = Xf; dst = Of; cc = t; }
    else        { cc = t - nf; if (cc >= ni) return; src = Xi; dst = Oi; }
    int rlid = cc & 15;
    int t2 = cc >> 4;
    int qd = t2 & 3;
    int t3 = t2 >> 2;
    int kt = t3 % 24;
    int p  = t3 / 24;
    const float* sp = src + (size_t)(p * 16 + rlid) * DC + kt * 32 + qd * 8;
    float4 a = *(const float4*)sp;
    float4 b = *(const float4*)(sp + 4);
    uint4 o;
    o.x = pk2(a.x, a.y); o.y = pk2(a.z, a.w);
    o.z = pk2(b.x, b.y); o.w = pk2(b.z, b.w);
    *(uint4*)(dst + (size_t)cc * 8) = o;
}

#define BSTR 76   // epilogue bounce stride (bf16 elems), conflict-free

// ---------- MFMA projection GEMM (round-0 baseline: fastest measured) ----------
// A: swizzled Xs, loaded DIRECTLY global->frag (coalesced 1KB bursts, no LDS).
// B: gll16-staged LDS. Merged feats+inps launch: blockIdx.x < 64 -> feats.
// Small LDS (9.7 KB) keeps ~4 blocks/CU resident: inter-block TLP covers the
// per-step drains (measured better than deep-pipeline variants, R1/R2).
__global__ __launch_bounds__(256, 3) void gemm_proj_mfma(
    const uint16_t* __restrict__ Xsf, const uint16_t* __restrict__ Xsi,
    const uint16_t* __restrict__ Wt,
    const float* __restrict__ b_f, const float* __restrict__ b_i,
    uint16_t* __restrict__ Pf, uint16_t* __restrict__ Pi)
{
    __shared__ union {
        uint16_t B[128 * 32];                 // 8 KB staging
        uint16_t bounce[4][16 * BSTR];        // 9.5 KB epilogue
    } sm;
    const int tid = threadIdx.x;
    const int w = tid >> 6, l = tid & 63;
    const bool isf = (blockIdx.x < 64);
    const int mx = isf ? blockIdx.x : blockIdx.x - 64;
    const int m0 = mx * 128;
    const int T  = isf ? T1C : T2C;
    const uint16_t* Xs = isf ? Xsf : Xsi;
    const float* bias  = isf ? b_f : b_i;
    uint16_t* P        = isf ? Pf : Pi;
    const int vmask    = isf ? 0x24 : 0x22;
    const int k6 = blockIdx.y / 6, nt = blockIdx.y % 6;
    const int n0 = nt * 128;
    const uint16_t* Bsrc = Wt + (size_t)((isf ? 0 : 6) + k6) * DC * DC;

    const int lid = l & 15, qd = l >> 4;
    const int wm = w >> 1, wn = w & 1;
    const int br = l >> 2, bk = (l & 3) * 8;
    const int p0 = mx * 8 + wm * 4;           // A panel base for this wave

    f32x4 acc[4][4] = {};

    for (int kt = 0; kt < DC / 32; ++kt) {
        __syncthreads();                       // prev iter's B reads done
#pragma unroll
        for (int n = 0; n < 2; ++n) {
            int c = w * 2 + n;
            gll16(Bsrc + (size_t)(n0 + c * 16 + br) * DC + kt * 32 + bk, &sm.B[c * 512]);
        }
        bf16x8 af[4];
#pragma unroll
        for (int i = 0; i < 4; i++)
            af[i] = *(const bf16x8*)(Xs + ((size_t)((p0 + i) * 24 + kt) * 64 + l) * 8);
        __syncthreads();                       // DMA drained
        bf16x8 bf[4];
#pragma unroll
        for (int j = 0; j < 4; j++)
            bf[j] = *(const bf16x8*)&sm.B[(wn * 64 + j * 16 + lid) * 32 + qd * 8];
#pragma unroll
        for (int i = 0; i < 4; i++)
#pragma unroll
            for (int j = 0; j < 4; j++)
                acc[i][j] = __builtin_amdgcn_mfma_f32_16x16x32_bf16(af[i], bf[j], acc[i][j], 0, 0, 0);
    }

    float bv[4];
#pragma unroll
    for (int j = 0; j < 4; j++)
        bv[j] = bias[k6 * DC + n0 + wn * 64 + j * 16 + lid];
    __syncthreads();   // all waves' K-loop LDS reads done before bounce overwrite

    uint16_t* reg = sm.bounce[w];
    const int mb = m0 + wm * 64;
    const int b = mb / T, tb = mb - b * T;     // 64-row wave tile never crosses b
    const int h = nt * 2 + wn;
    const int rrow = l >> 2;                   // readback row within pass
    const int rcol = (l & 3) * 16;             // readback col chunk

    if (!((vmask >> k6) & 1)) {
        // normal [t][e]: pass p = m-rows p*16..p*16+15 (i = p)
        uint16_t* dst0 = P + ((((size_t)k6 * BB + b) * HC + h) * T + tb + rrow) * EC + rcol;
#pragma unroll
        for (int p = 0; p < 4; p++) {
#pragma unroll
            for (int j = 0; j < 4; j++)
#pragma unroll
                for (int r = 0; r < 4; r++)
                    reg[(qd * 4 + r) * BSTR + j * 16 + lid] =
                        f2b((acc[p][j][r] + bv[j]) * QSCALE);
            uint4 d0 = *(const uint4*)&reg[rrow * BSTR + rcol];
            uint4 d1 = *(const uint4*)&reg[rrow * BSTR + rcol + 8];
            uint16_t* dst = dst0 + (size_t)p * 16 * EC;
            *(uint4*)dst = d0;
            *(uint4*)(dst + 8) = d1;
        }
    } else {
        // transposed [e][t]: pass p = e-rows p*16..p*16+15 (j = p)
        uint16_t* dst0 = P + (size_t)k6 * BB * HC * T * EC
                           + (((size_t)b * HC + h) * EC + rrow) * T + tb + rcol;
#pragma unroll
        for (int p = 0; p < 4; p++) {
#pragma unroll
            for (int i = 0; i < 4; i++) {
                uint32_t w0 = pk2((acc[i][p][0] + bv[p]) * QSCALE,
                                  (acc[i][p][1] + bv[p]) * QSCALE);
                uint32_t w1 = pk2((acc[i][p][2] + bv[p]) * QSCALE,
                                  (acc[i][p][3] + bv[p]) * QSCALE);
                *(uint2*)&reg[lid * BSTR + i * 16 + qd * 4] = make_uint2(w0, w1);
            }
            uint4 d0 = *(const uint4*)&reg[rrow * BSTR + rcol];
            uint4 d1 = *(const uint4*)&reg[rrow * BSTR + rcol + 8];
            uint16_t* dst = dst0 + (size_t)p * 16 * T;
            *(uint4*)dst = d0;
            *(uint4*)(dst + 8) = d1;
        }
    }
}

// ---------- MFMA output GEMM ----------
// A = attn output, PRE-SWIZZLED in frag order (written by attn) -> direct loads.
// Merged visual+language: blockIdx.x < 64 -> visual, else language.
__global__ __launch_bounds__(256, 3) void gemm_out_mfma(
    const uint16_t* __restrict__ Osv, const uint16_t* __restrict__ Osl,
    const uint16_t* __restrict__ Wt,
    const float* __restrict__ bu_v, const float* __restrict__ bu_l,
    float* __restrict__ out)
{
    __shared__ uint16_t Bs[128 * 32];
    const int tid = threadIdx.x;
    const int w = tid >> 6, l = tid & 63;
    const bool isv = (blockIdx.x < 64);
    const int mx = isv ? blockIdx.x : blockIdx.x - 64;
    const int m0 = mx * 128;
    const int rowoff = isv ? 0 : BB * T1C;
    const uint16_t* A = isv ? Osv : Osl;
    const uint16_t* Wtm = Wt + (size_t)(isv ? 12 : 13) * DC * DC;
    const float* bias = isv ? bu_v : bu_l;
    const int n0 = blockIdx.y * 128;
    const int lid = l & 15, qd = l >> 4;
    const int wm = w >> 1, wn = w & 1;
    const int br = l >> 2, bk = (l & 3) * 8;
    const int p0 = mx * 8 + wm * 4;

    f32x4 acc[4][4] = {};

    for (int kt = 0; kt < DC / 32; ++kt) {
        __syncthreads();
#pragma unroll
        for (int n = 0; n < 2; ++n) {
            int c = w * 2 + n;
            gll16(Wtm + (size_t)(n0 + c * 16 + br) * DC + kt * 32 + bk, &Bs[c * 512]);
        }
        bf16x8 af[4];
#pragma unroll
        for (int i = 0; i < 4; i++)
            af[i] = *(const bf16x8*)(A + ((size_t)((p0 + i) * 24 + kt) * 64 + l) * 8);
        __syncthreads();
        bf16x8 bf[4];
#pragma unroll
        for (int j = 0; j < 4; j++)
            bf[j] = *(const bf16x8*)&Bs[(wn * 64 + j * 16 + lid) * 32 + qd * 8];
#pragma unroll
        for (int i = 0; i < 4; i++)
#pragma unroll
            for (int j = 0; j < 4; j++)
                acc[i][j] = __builtin_amdgcn_mfma_f32_16x16x32_bf16(af[i], bf[j], acc[i][j], 0, 0, 0);
    }

    float bv[4];
#pragma unroll
    for (int j = 0; j < 4; j++)
        bv[j] = bias[n0 + wn * 64 + j * 16 + lid];
#pragma unroll
    for (int i = 0; i < 4; i++)
#pragma unroll
        for (int j = 0; j < 4; j++)
#pragma unroll
            for (int r = 0; r < 4; r++) {
                int m = m0 + wm * 64 + i * 16 + qd * 4 + r;
                int f = n0 + wn * 64 + j * 16 + lid;
                out[(size_t)(rowoff + m) * DC + f] = acc[i][j][r] + bv[j];
            }
}

// ---------- MFMA flash attention: reg-prefetch double-buffered staging ----------
// grid (192 bh, 9 tiles): 192%8==0 => all 9 tiles of one bh map to the SAME
// XCD for K/V L2 reuse. Per chunk: issue chunk c+1's K/V global loads into
// regs BEFORE chunk c's barriers (T14 issue-early/write-late); ds_write chunk
// c's regs after a raw s_barrier (no vmcnt drain, so c+1's loads stay in
// flight under chunk c's compute); publish with lgkmcnt(0)+s_barrier.
// Fully unrolled -> all double-buffer reg indices static (rule #20).
__global__ __launch_bounds__(256, 3) void attn_mfma(
    const uint16_t* __restrict__ Pf,
    const uint16_t* __restrict__ Pi,
    const void* __restrict__ maskp,
    const int* __restrict__ flags,
    uint16_t* __restrict__ Osv,        // swizzled visual O (M=8192)
    uint16_t* __restrict__ Osl)        // swizzled language O (M=1024)
{
    __shared__ uint16_t Klds[64 * 72];      // [key][e]
    __shared__ uint16_t Vlds[64 * 72];      // [e][key]
    __shared__ uint16_t Plds[4][16 * 72];   // per-wave P [q][key]
    __shared__ float    Ma[SC];
    __shared__ float    Lw[4][16];

    const int bh = blockIdx.x;
    const int tile = blockIdx.y;
    const int b = bh / HC, h = bh % HC;
    const int tid = threadIdx.x;
    const int w = tid >> 6, l = tid & 63;
    const int lid = l & 15, qd = l >> 4;

    const size_t SF = (size_t)BB * HC * T1C * EC;
    const size_t SI = (size_t)BB * HC * T2C * EC;

    const bool vis = (tile < 8);
    const uint16_t *Qa, *Qb, *K1, *K2, *V1, *V2;
    uint16_t* O; int Tq, q0;
    if (vis) { Qa = Pf + 1 * SF; Qb = Pf + 3 * SF; K1 = Pf;          K2 = Pi;
               V1 = Pf + 2 * SF; V2 = Pi + 1 * SI; O = Osv; Tq = T1C; q0 = tile * 64; }
    else     { Qa = Pi + 2 * SI; Qb = Pi + 3 * SI; K1 = Pf + 4 * SF; K2 = Pi + 4 * SI;
               V1 = Pf + 5 * SF; V2 = Pi + 5 * SI; O = Osl; Tq = T2C; q0 = 0; }

    {
        const int kind = flags[0];
        for (int i = tid; i < SC; i += 256) {
            int idx = b * SC + i;
            int mv;
            if (kind == 0)      mv = ((const uint32_t*)maskp)[idx] != 0u;
            else if (kind == 1) mv = ((const uint8_t*)maskp)[idx] != 0;
            else                mv = ((const uint16_t*)maskp)[idx] != 0;
            Ma[i] = mv ? -1e9f : 0.0f;
        }
    }

    // preload BOTH Q variants (the 9th chunk switches query matrix)
    const int q = q0 + w * 16 + lid;
    const uint16_t* Qrow  = Qa + ((size_t)bh * Tq + q) * EC;
    const uint16_t* Qrow2 = Qb + ((size_t)bh * Tq + q) * EC;
    bf16x8 qf0 = *(const bf16x8*)(Qrow + qd * 8);
    bf16x8 qf1 = *(const bf16x8*)(Qrow + 32 + qd * 8);
    bf16x8 qg0 = *(const bf16x8*)(Qrow2 + qd * 8);
    bf16x8 qg1 = *(const bf16x8*)(Qrow2 + 32 + qd * 8);

    f32x4 o[4];
#pragma unroll
    for (int ef = 0; ef < 4; ef++) { o[ef][0]=0.f; o[ef][1]=0.f; o[ef][2]=0.f; o[ef][3]=0.f; }
    float u[4] = {0.f, 0.f, 0.f, 0.f};

    const int skey = tid >> 2, se0 = (tid & 3) * 16;   // K stage (row, col chunk)
    const int ve = tid >> 2,  vc = tid & 3;            // V stage (e-row, key chunk)

    // chunk-c staging source addresses (c compile-time under full unroll)
    auto kptr = [&](int c) -> const uint16_t* {
        return (c < 8) ? K1 + ((size_t)bh * T1C + c * 64 + skey) * EC + se0
                       : K2 + ((size_t)bh * T2C + skey) * EC + se0;
    };
    auto vptr = [&](int c) -> const uint16_t* {
        return (c < 8) ? V1 + ((size_t)bh * EC + ve) * T1C + c * 64 + vc * 16
                       : V2 + ((size_t)bh * EC + ve) * T2C + vc * 16;
    };

    // prologue: issue chunk 0 loads into current regs
    uint4 ka0 = *(const uint4*)kptr(0);
    uint4 ka1 = *(const uint4*)(kptr(0) + 8);
    uint4 va0 = *(const uint4*)vptr(0);
    uint4 va1 = *(const uint4*)(vptr(0) + 8);

#pragma unroll
    for (int c = 0; c < 9; ++c) {
        // issue next chunk's loads FIRST (newer in vmcnt order; the compiler's
        // auto-wait before the ds_writes below then only drains chunk c's loads)
        uint4 kb0, kb1, vb0, vb1;
        if (c < 8) {
            kb0 = *(const uint4*)kptr(c + 1);
            kb1 = *(const uint4*)(kptr(c + 1) + 8);
            vb0 = *(const uint4*)vptr(c + 1);
            vb1 = *(const uint4*)(vptr(c + 1) + 8);
        }
        __builtin_amdgcn_s_barrier();              // prev chunk LDS reads done
        __builtin_amdgcn_sched_barrier(0);
        *(uint4*)&Klds[skey * 72 + se0]         = ka0;
        *(uint4*)&Klds[skey * 72 + se0 + 8]     = ka1;
        *(uint4*)&Vlds[ve * 72 + vc * 16]       = va0;
        *(uint4*)&Vlds[ve * 72 + vc * 16 + 8]   = va1;
        asm volatile("s_waitcnt lgkmcnt(0)" ::: "memory");
        __builtin_amdgcn_sched_barrier(0);
        __builtin_amdgcn_s_barrier();              // publish K/V (and Ma @c=0)
        __builtin_amdgcn_sched_barrier(0);

        const int k0 = c * 64;
        const bf16x8 q_0 = (c < 8) ? qf0 : qg0;
        const bf16x8 q_1 = (c < 8) ? qf1 : qg1;
        // QK^T: D[q][key]
        f32x4 s[4];
#pragma unroll
        for (int sub = 0; sub < 4; sub++) {
            bf16x8 kf0 = *(const bf16x8*)&Klds[(sub * 16 + lid) * 72 + qd * 8];
            bf16x8 kf1 = *(const bf16x8*)&Klds[(sub * 16 + lid) * 72 + 32 + qd * 8];
            f32x4 z; z[0]=0.f; z[1]=0.f; z[2]=0.f; z[3]=0.f;
            z = __builtin_amdgcn_mfma_f32_16x16x32_bf16(q_0, kf0, z, 0, 0, 0);
            s[sub] = __builtin_amdgcn_mfma_f32_16x16x32_bf16(q_1, kf1, z, 0, 0, 0);
        }
        // p = exp(s + mask); accumulate row-sum; write P (C-layout -> [q][key])
#pragma unroll
        for (int sub = 0; sub < 4; sub++) {
            float mv = Ma[k0 + sub * 16 + lid];
#pragma unroll
            for (int r = 0; r < 4; r++) {
                float p = __expf(s[sub][r] + mv);
                u[r] += p;
                Plds[w][(qd * 4 + r) * 72 + sub * 16 + lid] = f2bfast(p);
            }
        }
        // PV as O^T = Vt * P^T (wave-local Plds round trip, no barrier)
#pragma unroll
        for (int half = 0; half < 2; half++) {
            bf16x8 pf = *(const bf16x8*)&Plds[w][lid * 72 + half * 32 + qd * 8];
#pragma unroll
            for (int ef = 0; ef < 4; ef++) {
                bf16x8 vf = *(const bf16x8*)&Vlds[(ef * 16 + lid) * 72 + half * 32 + qd * 8];
                o[ef] = __builtin_amdgcn_mfma_f32_16x16x32_bf16(vf, pf, o[ef], 0, 0, 0);
            }
        }
        if (c < 8) { ka0 = kb0; ka1 = kb1; va0 = vb0; va1 = vb1; }
    }

    // one-time row-sum reduction across key-lanes (bits 0-3)
#pragma unroll
    for (int d = 1; d <= 8; d <<= 1)
#pragma unroll
        for (int r = 0; r < 4; r++)
            u[r] += __shfl_xor(u[r], d, 64);
    if (lid == 0) {
#pragma unroll
        for (int r = 0; r < 4; r++) Lw[w][qd * 4 + r] = u[r];
    }
    float rl = 1.f / Lw[w][lid];   // l for this lane's query (wave-local ordering)

    // O write in gemm_out's swizzled A-frag order:
    // m = b*Tq + q; panel p = m>>4 (wave-uniform), rlid = lid.
    // col = h*64 + e, e = ef*16 + qd*4 + r  ->  kt = h*2 + (ef>>1),
    // cq = (ef&1)*2 + (qd>>1), j = (qd&1)*4 + r  -> one 8B store per ef.
    const size_t p = ((size_t)b * Tq + q0 + w * 16) >> 4;
#pragma unroll
    for (int ef = 0; ef < 4; ef++) {
        uint32_t w0 = pk2(o[ef][0] * rl, o[ef][1] * rl);
        uint32_t w1 = pk2(o[ef][2] * rl, o[ef][3] * rl);
        size_t chunk = ((p * 24 + h * 2 + (ef >> 1)) * 4 + (ef & 1) * 2 + (qd >> 1)) * 16 + lid;
        *(uint2*)(O + chunk * 8 + (qd & 1) * 4) = make_uint2(w0, w1);
    }
}

// ---------- launch ----------
extern "C" void kernel_launch(void* const* d_in, const int* in_sizes, int n_in,
                              void* d_out, int out_size, void* d_ws, size_t ws_size,
                              hipStream_t stream)
{
    const float* feats = (const float*)d_in[0];
    const float* inps  = (const float*)d_in[1];
    const void*  maskp = d_in[2];
    const float* W_f   = (const float*)d_in[3];
    const float* b_f   = (const float*)d_in[4];
    const float* W_i   = (const float*)d_in[5];
    const float* b_i   = (const float*)d_in[6];
    const float* Wu_v  = (const float*)d_in[7];
    const float* bu_v  = (const float*)d_in[8];
    const float* Wu_l  = (const float*)d_in[9];
    const float* bu_l  = (const float*)d_in[10];

    const size_t MAT = (size_t)DC * DC;               // 589824
    const size_t PF_E = 6ull * BB * HC * T1C * EC;
    const size_t PI_E = 6ull * BB * HC * T2C * EC;
    uint16_t* Wt  = (uint16_t*)d_ws;
    uint16_t* Osv = Wt;                               // reuses dead Wt[0..11]
    uint16_t* Osl = Wt + (size_t)BB * T1C * HC * EC;
    uint16_t* Pf  = Wt + 14 * MAT;
    uint16_t* Pi  = Pf + PF_E;
    int* flags    = (int*)(Pi + PI_E);

    // Swizzled bf16 X lives in d_out's first ~21 MB: d_out is only written by
    // the final gemm_out launch (stream-ordered after all Xs reads).
    uint16_t* Xsf = (uint16_t*)d_out;
    uint16_t* Xsi = Xsf + (size_t)BB * T1C * DC;

    detect<<<dim3(1), dim3(256), 0, stream>>>((const uint32_t*)maskp, flags);

    wtrans<<<dim3(24, 24, 14), dim3(256), 0, stream>>>(W_f, W_i, Wu_v, Wu_l, Wt);

    {
        int nchunks = (BB * T1C * DC + BB * T2C * DC) / 8;
        xswz<<<dim3((nchunks + 255) / 256), dim3(256), 0, stream>>>(feats, inps, Xsf, Xsi);
    }

    gemm_proj_mfma<<<dim3(72, 36), dim3(256), 0, stream>>>(
        Xsf, Xsi, Wt, b_f, b_i, Pf, Pi);

    attn_mfma<<<dim3(BB * HC, 9), dim3(256), 0, stream>>>(
        Pf, Pi, maskp, flags, Osv, Osl);

    gemm_out_mfma<<<dim3(72, 6), dim3(256), 0, stream>>>(
        Osv, Osl, Wt, bu_v, bu_l, (float*)d_out);
}

// Round 4
// 264.366 us; speedup vs baseline: 1.0789x; 1.0237x over previous
//
#include <hip/hip_runtime.h>
#include <stdint.h>

// Problem constants
#define BB 16
#define T1C 512
#define T2C 64
#define DC 768
#define HC 12
#define EC 64
#define SC 576          // T1+T2
#define QSCALE 0.35355339059327379f   // 64^-0.25

typedef __attribute__((ext_vector_type(8))) short bf16x8;   // 8 bf16 = 4 VGPRs
typedef __attribute__((ext_vector_type(4))) float f32x4;    // MFMA C/D

// ---------- bf16 helpers ----------
__device__ __forceinline__ uint16_t f2b(float f) {          // RNE
    union { float f; uint32_t i; } v; v.f = f;
    return (uint16_t)((v.i + 0x7fffu + ((v.i >> 16) & 1u)) >> 16);
}
__device__ __forceinline__ uint16_t f2bfast(float f) {      // round-half-up (cheap)
    union { float f; uint32_t i; } v; v.f = f;
    return (uint16_t)((v.i + 0x8000u) >> 16);
}
__device__ __forceinline__ uint32_t pk2(float a, float b) {
    return (uint32_t)f2b(a) | ((uint32_t)f2b(b) << 16);
}

// async global->LDS, 16B per lane; LDS dest = wave-uniform base + lane*16
__device__ __forceinline__ void gll16(const void* g, void* l) {
    __builtin_amdgcn_global_load_lds(
        (const __attribute__((address_space(1))) uint32_t*)(uintptr_t)g,
        (__attribute__((address_space(3))) uint32_t*)(uintptr_t)l, 16, 0, 0);
}

// ---------- mask layout detection (deterministic -> graph-safe) ----------
__global__ void detect(const uint32_t* __restrict__ mw, int* __restrict__ flags) {
    __shared__ int aW, aB, aL;
    if (threadIdx.x == 0) { aW = 0; aB = 0; aL = 0; }
    __syncthreads();
    int lW = 0, lB = 0, lL = 0;
    for (int i = threadIdx.x; i < 2304; i += 256) {
        uint32_t w = mw[i];
        if (w > 1u) lW = 1;
        if (((w) & 0xffu) > 1u || ((w >> 8) & 0xffu) > 1u ||
            ((w >> 16) & 0xffu) > 1u || ((w >> 24) & 0xffu) > 1u) lB = 1;
        if ((w & 0xffffu) > 1u) lL = 1;
    }
    if (lW) atomicOr(&aW, 1);
    if (lB) atomicOr(&aB, 1);
    if (lL) atomicOr(&aL, 1);
    __syncthreads();
    if (threadIdx.x == 0)
        flags[0] = (!aW) ? 0 : ((!aB) ? 1 : (aL ? 2 : 0));
}

// ---------- weight transpose + f32->bf16 ----------
// Wt[z][f][k] = W_z[k][f] bf16; z: 0..5 = W_f, 6..11 = W_i, 12 = Wu_v, 13 = Wu_l
__global__ __launch_bounds__(256) void wtrans(
    const float* __restrict__ Wf, const float* __restrict__ Wi,
    const float* __restrict__ Wuv, const float* __restrict__ Wul,
    uint16_t* __restrict__ Wt)
{
    __shared__ float tile[32][33];
    const int z = blockIdx.z;
    const float* src = (z < 6)  ? Wf + (size_t)z * DC * DC
                     : (z < 12) ? Wi + (size_t)(z - 6) * DC * DC
                     : (z == 12 ? Wuv : Wul);
    uint16_t* dst = Wt + (size_t)z * DC * DC;
    const int tx = threadIdx.x & 31, ty = threadIdx.x >> 5;
    const int k0 = blockIdx.x * 32, f0 = blockIdx.y * 32;
#pragma unroll
    for (int r = 0; r < 4; r++)
        tile[ty + r * 8][tx] = src[(size_t)(k0 + ty + r * 8) * DC + f0 + tx];
    __syncthreads();
#pragma unroll
    for (int r = 0; r < 4; r++)
        dst[(size_t)(f0 + ty + r * 8) * DC + k0 + tx] = f2b(tile[tx][ty + r * 8]);
}

// ---------- X f32 -> bf16 swizzle prepass (MFMA A-fragment order) ----------
// chunk cc (8 elems): cc = ((p*24 + kt)*4 + qd)*16 + rlid
// holds X[p*16+rlid][kt*32 + qd*8 .. +7]. A frag load for (panel p, kt) is then
// 64 lanes x contiguous 16B = one coalesced 1KB burst.
__global__ __launch_bounds__(256) void xswz(
    const float* __restrict__ Xf, const float* __restrict__ Xi,
    uint16_t* __restrict__ Of, uint16_t* __restrict__ Oi)
{
    const int nf = BB * T1C * DC / 8;
    const int ni = BB * T2C * DC / 8;
    int t = blockIdx.x * 256 + threadIdx.x;
    const float* src; uint16_t* dst; int cc;
    if (t < nf) { src = Xf; dst = Of; cc = t; }
    else        { cc = t - nf; if (cc >= ni) return; src = Xi; dst = Oi; }
    int rlid = cc & 15;
    int t2 = cc >> 4;
    int qd = t2 & 3;
    int t3 = t2 >> 2;
    int kt = t3 % 24;
    int p  = t3 / 24;
    const float* sp = src + (size_t)(p * 16 + rlid) * DC + kt * 32 + qd * 8;
    float4 a = *(const float4*)sp;
    float4 b = *(const float4*)(sp + 4);
    uint4 o;
    o.x = pk2(a.x, a.y); o.y = pk2(a.z, a.w);
    o.z = pk2(b.x, b.y); o.w = pk2(b.z, b.w);
    *(uint4*)(dst + (size_t)cc * 8) = o;
}

#define BSTR 76   // epilogue bounce stride (bf16 elems), conflict-free

// ---------- MFMA projection GEMM ----------
// R0 structure (128x128, 4 waves, small LDS, direct-global A-frags) +
//  * __launch_bounds__(256,4): cap VGPR+AGPR at 128/wave -> 4 blocks/CU.
//  * B double-buffer (2 x 8KB, BK=32) with counted vmcnt: the pre-barrier
//    wait is vmcnt(2) on DMA issued ONE ITERATION ago (in flight across the
//    whole previous compute), not a drain of just-issued loads.
// Queue invariant at the vmcnt point: [stage(t)x2, A(t)x4, stage(t+1)x2];
// vmcnt(2) retires stage(t)+A(t), leaves stage(t+1) in flight.
__global__ __launch_bounds__(256, 4) void gemm_proj_mfma(
    const uint16_t* __restrict__ Xsf, const uint16_t* __restrict__ Xsi,
    const uint16_t* __restrict__ Wt,
    const float* __restrict__ b_f, const float* __restrict__ b_i,
    uint16_t* __restrict__ Pf, uint16_t* __restrict__ Pi)
{
    __shared__ union {
        uint16_t B[2][128 * 32];              // 16 KB double-buffered staging
        uint16_t bounce[4][16 * BSTR];        // 9.5 KB epilogue
    } sm;
    const int tid = threadIdx.x;
    const int w = tid >> 6, l = tid & 63;
    const bool isf = (blockIdx.x < 64);
    const int mx = isf ? blockIdx.x : blockIdx.x - 64;
    const int m0 = mx * 128;
    const int T  = isf ? T1C : T2C;
    const uint16_t* Xs = isf ? Xsf : Xsi;
    const float* bias  = isf ? b_f : b_i;
    uint16_t* P        = isf ? Pf : Pi;
    const int vmask    = isf ? 0x24 : 0x22;
    const int k6 = blockIdx.y / 6, nt = blockIdx.y % 6;
    const int n0 = nt * 128;
    const uint16_t* Bsrc = Wt + (size_t)((isf ? 0 : 6) + k6) * DC * DC;

    const int lid = l & 15, qd = l >> 4;
    const int wm = w >> 1, wn = w & 1;
    const int br = l >> 2, bk = (l & 3) * 8;
    const int p0 = mx * 8 + wm * 4;           // A panel base for this wave
    const int c0 = w * 2;                     // this wave's two staging chunks

    f32x4 acc[4][4] = {};

    // prologue: stage tile 0 into buf0 (2 gll16/wave outstanding)
#pragma unroll
    for (int n = 0; n < 2; ++n)
        gll16(Bsrc + (size_t)(n0 + (c0 + n) * 16 + br) * DC + bk, &sm.B[0][(c0 + n) * 512]);

    for (int kt = 0; kt < DC / 32; ++kt) {
        uint16_t* Bcur = sm.B[kt & 1];
        uint16_t* Bnxt = sm.B[(kt + 1) & 1];
        // A-frags for this tile (issued now, in flight across barrier #1)
        bf16x8 af[4];
#pragma unroll
        for (int i = 0; i < 4; i++)
            af[i] = *(const bf16x8*)(Xs + ((size_t)((p0 + i) * 24 + kt) * 64 + l) * 8);
        __builtin_amdgcn_s_barrier();          // all waves done reading Bnxt (buf of kt-1)
        __builtin_amdgcn_sched_barrier(0);
        if (kt < 23) {
#pragma unroll
            for (int n = 0; n < 2; ++n)
                gll16(Bsrc + (size_t)(n0 + (c0 + n) * 16 + br) * DC + (kt + 1) * 32 + bk,
                      &Bnxt[(c0 + n) * 512]);
            asm volatile("s_waitcnt vmcnt(2)" ::: "memory");   // stage(kt)+A(kt) done
        } else {
            asm volatile("s_waitcnt vmcnt(0)" ::: "memory");   // final drain
        }
        __builtin_amdgcn_sched_barrier(0);
        __builtin_amdgcn_s_barrier();          // publish B(kt) cross-wave
        __builtin_amdgcn_sched_barrier(0);
        bf16x8 bf[4];
#pragma unroll
        for (int j = 0; j < 4; j++)
            bf[j] = *(const bf16x8*)&Bcur[(wn * 64 + j * 16 + lid) * 32 + qd * 8];
#pragma unroll
        for (int i = 0; i < 4; i++)
#pragma unroll
            for (int j = 0; j < 4; j++)
                acc[i][j] = __builtin_amdgcn_mfma_f32_16x16x32_bf16(af[i], bf[j], acc[i][j], 0, 0, 0);
    }

    float bv[4];
#pragma unroll
    for (int j = 0; j < 4; j++)
        bv[j] = bias[k6 * DC + n0 + wn * 64 + j * 16 + lid];
    __syncthreads();   // all waves' K-loop LDS reads done before bounce overwrite

    uint16_t* reg = sm.bounce[w];
    const int mb = m0 + wm * 64;
    const int b = mb / T, tb = mb - b * T;     // 64-row wave tile never crosses b
    const int h = nt * 2 + wn;
    const int rrow = l >> 2;                   // readback row within pass
    const int rcol = (l & 3) * 16;             // readback col chunk

    if (!((vmask >> k6) & 1)) {
        // normal [t][e]: pass p = m-rows p*16..p*16+15 (i = p)
        uint16_t* dst0 = P + ((((size_t)k6 * BB + b) * HC + h) * T + tb + rrow) * EC + rcol;
#pragma unroll
        for (int p = 0; p < 4; p++) {
#pragma unroll
            for (int j = 0; j < 4; j++)
#pragma unroll
                for (int r = 0; r < 4; r++)
                    reg[(qd * 4 + r) * BSTR + j * 16 + lid] =
                        f2b((acc[p][j][r] + bv[j]) * QSCALE);
            uint4 d0 = *(const uint4*)&reg[rrow * BSTR + rcol];
            uint4 d1 = *(const uint4*)&reg[rrow * BSTR + rcol + 8];
            uint16_t* dst = dst0 + (size_t)p * 16 * EC;
            *(uint4*)dst = d0;
            *(uint4*)(dst + 8) = d1;
        }
    } else {
        // transposed [e][t]: pass p = e-rows p*16..p*16+15 (j = p)
        uint16_t* dst0 = P + (size_t)k6 * BB * HC * T * EC
                           + (((size_t)b * HC + h) * EC + rrow) * T + tb + rcol;
#pragma unroll
        for (int p = 0; p < 4; p++) {
#pragma unroll
            for (int i = 0; i < 4; i++) {
                uint32_t w0 = pk2((acc[i][p][0] + bv[p]) * QSCALE,
                                  (acc[i][p][1] + bv[p]) * QSCALE);
                uint32_t w1 = pk2((acc[i][p][2] + bv[p]) * QSCALE,
                                  (acc[i][p][3] + bv[p]) * QSCALE);
                *(uint2*)&reg[lid * BSTR + i * 16 + qd * 4] = make_uint2(w0, w1);
            }
            uint4 d0 = *(const uint4*)&reg[rrow * BSTR + rcol];
            uint4 d1 = *(const uint4*)&reg[rrow * BSTR + rcol + 8];
            uint16_t* dst = dst0 + (size_t)p * 16 * T;
            *(uint4*)dst = d0;
            *(uint4*)(dst + 8) = d1;
        }
    }
}

// ---------- MFMA output GEMM ----------
// Same transform as gemm_proj: (256,4) + double-buffered B + counted vmcnt.
__global__ __launch_bounds__(256, 4) void gemm_out_mfma(
    const uint16_t* __restrict__ Osv, const uint16_t* __restrict__ Osl,
    const uint16_t* __restrict__ Wt,
    const float* __restrict__ bu_v, const float* __restrict__ bu_l,
    float* __restrict__ out)
{
    __shared__ uint16_t Bs[2][128 * 32];
    const int tid = threadIdx.x;
    const int w = tid >> 6, l = tid & 63;
    const bool isv = (blockIdx.x < 64);
    const int mx = isv ? blockIdx.x : blockIdx.x - 64;
    const int m0 = mx * 128;
    const int rowoff = isv ? 0 : BB * T1C;
    const uint16_t* A = isv ? Osv : Osl;
    const uint16_t* Wtm = Wt + (size_t)(isv ? 12 : 13) * DC * DC;
    const float* bias = isv ? bu_v : bu_l;
    const int n0 = blockIdx.y * 128;
    const int lid = l & 15, qd = l >> 4;
    const int wm = w >> 1, wn = w & 1;
    const int br = l >> 2, bk = (l & 3) * 8;
    const int p0 = mx * 8 + wm * 4;
    const int c0 = w * 2;

    f32x4 acc[4][4] = {};

    // prologue: stage tile 0 into buf0
#pragma unroll
    for (int n = 0; n < 2; ++n)
        gll16(Wtm + (size_t)(n0 + (c0 + n) * 16 + br) * DC + bk, &Bs[0][(c0 + n) * 512]);

    for (int kt = 0; kt < DC / 32; ++kt) {
        uint16_t* Bcur = Bs[kt & 1];
        uint16_t* Bnxt = Bs[(kt + 1) & 1];
        bf16x8 af[4];
#pragma unroll
        for (int i = 0; i < 4; i++)
            af[i] = *(const bf16x8*)(A + ((size_t)((p0 + i) * 24 + kt) * 64 + l) * 8);
        __builtin_amdgcn_s_barrier();
        __builtin_amdgcn_sched_barrier(0);
        if (kt < 23) {
#pragma unroll
            for (int n = 0; n < 2; ++n)
                gll16(Wtm + (size_t)(n0 + (c0 + n) * 16 + br) * DC + (kt + 1) * 32 + bk,
                      &Bnxt[(c0 + n) * 512]);
            asm volatile("s_waitcnt vmcnt(2)" ::: "memory");
        } else {
            asm volatile("s_waitcnt vmcnt(0)" ::: "memory");
        }
        __builtin_amdgcn_sched_barrier(0);
        __builtin_amdgcn_s_barrier();
        __builtin_amdgcn_sched_barrier(0);
        bf16x8 bf[4];
#pragma unroll
        for (int j = 0; j < 4; j++)
            bf[j] = *(const bf16x8*)&Bcur[(wn * 64 + j * 16 + lid) * 32 + qd * 8];
#pragma unroll
        for (int i = 0; i < 4; i++)
#pragma unroll
            for (int j = 0; j < 4; j++)
                acc[i][j] = __builtin_amdgcn_mfma_f32_16x16x32_bf16(af[i], bf[j], acc[i][j], 0, 0, 0);
    }

    float bv[4];
#pragma unroll
    for (int j = 0; j < 4; j++)
        bv[j] = bias[n0 + wn * 64 + j * 16 + lid];
#pragma unroll
    for (int i = 0; i < 4; i++)
#pragma unroll
        for (int j = 0; j < 4; j++)
#pragma unroll
            for (int r = 0; r < 4; r++) {
                int m = m0 + wm * 64 + i * 16 + qd * 4 + r;
                int f = n0 + wn * 64 + j * 16 + lid;
                out[(size_t)(rowoff + m) * DC + f] = acc[i][j][r] + bv[j];
            }
}

// ---------- MFMA flash attention: reg-prefetch double-buffered staging ----------
// grid (192 bh, 9 tiles): 192%8==0 => all 9 tiles of one bh map to the SAME
// XCD for K/V L2 reuse. Per chunk: issue chunk c+1's K/V global loads into
// regs BEFORE chunk c's barriers (T14 issue-early/write-late); ds_write chunk
// c's regs after a raw s_barrier; publish with lgkmcnt(0)+s_barrier.
__global__ __launch_bounds__(256, 3) void attn_mfma(
    const uint16_t* __restrict__ Pf,
    const uint16_t* __restrict__ Pi,
    const void* __restrict__ maskp,
    const int* __restrict__ flags,
    uint16_t* __restrict__ Osv,        // swizzled visual O (M=8192)
    uint16_t* __restrict__ Osl)        // swizzled language O (M=1024)
{
    __shared__ uint16_t Klds[64 * 72];      // [key][e]
    __shared__ uint16_t Vlds[64 * 72];      // [e][key]
    __shared__ uint16_t Plds[4][16 * 72];   // per-wave P [q][key]
    __shared__ float    Ma[SC];
    __shared__ float    Lw[4][16];

    const int bh = blockIdx.x;
    const int tile = blockIdx.y;
    const int b = bh / HC, h = bh % HC;
    const int tid = threadIdx.x;
    const int w = tid >> 6, l = tid & 63;
    const int lid = l & 15, qd = l >> 4;

    const size_t SF = (size_t)BB * HC * T1C * EC;
    const size_t SI = (size_t)BB * HC * T2C * EC;

    const bool vis = (tile < 8);
    const uint16_t *Qa, *Qb, *K1, *K2, *V1, *V2;
    uint16_t* O; int Tq, q0;
    if (vis) { Qa = Pf + 1 * SF; Qb = Pf + 3 * SF; K1 = Pf;          K2 = Pi;
               V1 = Pf + 2 * SF; V2 = Pi + 1 * SI; O = Osv; Tq = T1C; q0 = tile * 64; }
    else     { Qa = Pi + 2 * SI; Qb = Pi + 3 * SI; K1 = Pf + 4 * SF; K2 = Pi + 4 * SI;
               V1 = Pf + 5 * SF; V2 = Pi + 5 * SI; O = Osl; Tq = T2C; q0 = 0; }

    {
        const int kind = flags[0];
        for (int i = tid; i < SC; i += 256) {
            int idx = b * SC + i;
            int mv;
            if (kind == 0)      mv = ((const uint32_t*)maskp)[idx] != 0u;
            else if (kind == 1) mv = ((const uint8_t*)maskp)[idx] != 0;
            else                mv = ((const uint16_t*)maskp)[idx] != 0;
            Ma[i] = mv ? -1e9f : 0.0f;
        }
    }

    // preload BOTH Q variants (the 9th chunk switches query matrix)
    const int q = q0 + w * 16 + lid;
    const uint16_t* Qrow  = Qa + ((size_t)bh * Tq + q) * EC;
    const uint16_t* Qrow2 = Qb + ((size_t)bh * Tq + q) * EC;
    bf16x8 qf0 = *(const bf16x8*)(Qrow + qd * 8);
    bf16x8 qf1 = *(const bf16x8*)(Qrow + 32 + qd * 8);
    bf16x8 qg0 = *(const bf16x8*)(Qrow2 + qd * 8);
    bf16x8 qg1 = *(const bf16x8*)(Qrow2 + 32 + qd * 8);

    f32x4 o[4];
#pragma unroll
    for (int ef = 0; ef < 4; ef++) { o[ef][0]=0.f; o[ef][1]=0.f; o[ef][2]=0.f; o[ef][3]=0.f; }
    float u[4] = {0.f, 0.f, 0.f, 0.f};

    const int skey = tid >> 2, se0 = (tid & 3) * 16;   // K stage (row, col chunk)
    const int ve = tid >> 2,  vc = tid & 3;            // V stage (e-row, key chunk)

    // chunk-c staging source addresses (c compile-time under full unroll)
    auto kptr = [&](int c) -> const uint16_t* {
        return (c < 8) ? K1 + ((size_t)bh * T1C + c * 64 + skey) * EC + se0
                       : K2 + ((size_t)bh * T2C + skey) * EC + se0;
    };
    auto vptr = [&](int c) -> const uint16_t* {
        return (c < 8) ? V1 + ((size_t)bh * EC + ve) * T1C + c * 64 + vc * 16
                       : V2 + ((size_t)bh * EC + ve) * T2C + vc * 16;
    };

    // prologue: issue chunk 0 loads into current regs
    uint4 ka0 = *(const uint4*)kptr(0);
    uint4 ka1 = *(const uint4*)(kptr(0) + 8);
    uint4 va0 = *(const uint4*)vptr(0);
    uint4 va1 = *(const uint4*)(vptr(0) + 8);

#pragma unroll
    for (int c = 0; c < 9; ++c) {
        // issue next chunk's loads FIRST (newer in vmcnt order; the compiler's
        // auto-wait before the ds_writes below then only drains chunk c's loads)
        uint4 kb0, kb1, vb0, vb1;
        if (c < 8) {
            kb0 = *(const uint4*)kptr(c + 1);
            kb1 = *(const uint4*)(kptr(c + 1) + 8);
            vb0 = *(const uint4*)vptr(c + 1);
            vb1 = *(const uint4*)(vptr(c + 1) + 8);
        }
        __builtin_amdgcn_s_barrier();              // prev chunk LDS reads done
        __builtin_amdgcn_sched_barrier(0);
        *(uint4*)&Klds[skey * 72 + se0]         = ka0;
        *(uint4*)&Klds[skey * 72 + se0 + 8]     = ka1;
        *(uint4*)&Vlds[ve * 72 + vc * 16]       = va0;
        *(uint4*)&Vlds[ve * 72 + vc * 16 + 8]   = va1;
        asm volatile("s_waitcnt lgkmcnt(0)" ::: "memory");
        __builtin_amdgcn_sched_barrier(0);
        __builtin_amdgcn_s_barrier();              // publish K/V (and Ma @c=0)
        __builtin_amdgcn_sched_barrier(0);

        const int k0 = c * 64;
        const bf16x8 q_0 = (c < 8) ? qf0 : qg0;
        const bf16x8 q_1 = (c < 8) ? qf1 : qg1;
        // QK^T: D[q][key]
        f32x4 s[4];
#pragma unroll
        for (int sub = 0; sub < 4; sub++) {
            bf16x8 kf0 = *(const bf16x8*)&Klds[(sub * 16 + lid) * 72 + qd * 8];
            bf16x8 kf1 = *(const bf16x8*)&Klds[(sub * 16 + lid) * 72 + 32 + qd * 8];
            f32x4 z; z[0]=0.f; z[1]=0.f; z[2]=0.f; z[3]=0.f;
            z = __builtin_amdgcn_mfma_f32_16x16x32_bf16(q_0, kf0, z, 0, 0, 0);
            s[sub] = __builtin_amdgcn_mfma_f32_16x16x32_bf16(q_1, kf1, z, 0, 0, 0);
        }
        // p = exp(s + mask); accumulate row-sum; write P (C-layout -> [q][key])
#pragma unroll
        for (int sub = 0; sub < 4; sub++) {
            float mv = Ma[k0 + sub * 16 + lid];
#pragma unroll
            for (int r = 0; r < 4; r++) {
                float p = __expf(s[sub][r] + mv);
                u[r] += p;
                Plds[w][(qd * 4 + r) * 72 + sub * 16 + lid] = f2bfast(p);
            }
        }
        // PV as O^T = Vt * P^T (wave-local Plds round trip, no barrier)
#pragma unroll
        for (int half = 0; half < 2; half++) {
            bf16x8 pf = *(const bf16x8*)&Plds[w][lid * 72 + half * 32 + qd * 8];
#pragma unroll
            for (int ef = 0; ef < 4; ef++) {
                bf16x8 vf = *(const bf16x8*)&Vlds[(ef * 16 + lid) * 72 + half * 32 + qd * 8];
                o[ef] = __builtin_amdgcn_mfma_f32_16x16x32_bf16(vf, pf, o[ef], 0, 0, 0);
            }
        }
        if (c < 8) { ka0 = kb0; ka1 = kb1; va0 = vb0; va1 = vb1; }
    }

    // one-time row-sum reduction across key-lanes (bits 0-3)
#pragma unroll
    for (int d = 1; d <= 8; d <<= 1)
#pragma unroll
        for (int r = 0; r < 4; r++)
            u[r] += __shfl_xor(u[r], d, 64);
    if (lid == 0) {
#pragma unroll
        for (int r = 0; r < 4; r++) Lw[w][qd * 4 + r] = u[r];
    }
    float rl = 1.f / Lw[w][lid];   // l for this lane's query (wave-local ordering)

    // O write in gemm_out's swizzled A-frag order:
    // m = b*Tq + q; panel p = m>>4 (wave-uniform), rlid = lid.
    // col = h*64 + e, e = ef*16 + qd*4 + r  ->  kt = h*2 + (ef>>1),
    // cq = (ef&1)*2 + (qd>>1), j = (qd&1)*4 + r  -> one 8B store per ef.
    const size_t p = ((size_t)b * Tq + q0 + w * 16) >> 4;
#pragma unroll
    for (int ef = 0; ef < 4; ef++) {
        uint32_t w0 = pk2(o[ef][0] * rl, o[ef][1] * rl);
        uint32_t w1 = pk2(o[ef][2] * rl, o[ef][3] * rl);
        size_t chunk = ((p * 24 + h * 2 + (ef >> 1)) * 4 + (ef & 1) * 2 + (qd >> 1)) * 16 + lid;
        *(uint2*)(O + chunk * 8 + (qd & 1) * 4) = make_uint2(w0, w1);
    }
}

// ---------- launch ----------
extern "C" void kernel_launch(void* const* d_in, const int* in_sizes, int n_in,
                              void* d_out, int out_size, void* d_ws, size_t ws_size,
                              hipStream_t stream)
{
    const float* feats = (const float*)d_in[0];
    const float* inps  = (const float*)d_in[1];
    const void*  maskp = d_in[2];
    const float* W_f   = (const float*)d_in[3];
    const float* b_f   = (const float*)d_in[4];
    const float* W_i   = (const float*)d_in[5];
    const float* b_i   = (const float*)d_in[6];
    const float* Wu_v  = (const float*)d_in[7];
    const float* bu_v  = (const float*)d_in[8];
    const float* Wu_l  = (const float*)d_in[9];
    const float* bu_l  = (const float*)d_in[10];

    const size_t MAT = (size_t)DC * DC;               // 589824
    const size_t PF_E = 6ull * BB * HC * T1C * EC;
    const size_t PI_E = 6ull * BB * HC * T2C * EC;
    uint16_t* Wt  = (uint16_t*)d_ws;
    uint16_t* Osv = Wt;                               // reuses dead Wt[0..11]
    uint16_t* Osl = Wt + (size_t)BB * T1C * HC * EC;
    uint16_t* Pf  = Wt + 14 * MAT;
    uint16_t* Pi  = Pf + PF_E;
    int* flags    = (int*)(Pi + PI_E);

    // Swizzled bf16 X lives in d_out's first ~21 MB: d_out is only written by
    // the final gemm_out launch (stream-ordered after all Xs reads).
    uint16_t* Xsf = (uint16_t*)d_out;
    uint16_t* Xsi = Xsf + (size_t)BB * T1C * DC;

    detect<<<dim3(1), dim3(256), 0, stream>>>((const uint32_t*)maskp, flags);

    wtrans<<<dim3(24, 24, 14), dim3(256), 0, stream>>>(W_f, W_i, Wu_v, Wu_l, Wt);

    {
        int nchunks = (BB * T1C * DC + BB * T2C * DC) / 8;
        xswz<<<dim3((nchunks + 255) / 256), dim3(256), 0, stream>>>(feats, inps, Xsf, Xsi);
    }

    gemm_proj_mfma<<<dim3(72, 36), dim3(256), 0, stream>>>(
        Xsf, Xsi, Wt, b_f, b_i, Pf, Pi);

    attn_mfma<<<dim3(BB * HC, 9), dim3(256), 0, stream>>>(
        Pf, Pi, maskp, flags, Osv, Osl);

    gemm_out_mfma<<<dim3(72, 6), dim3(256), 0, stream>>>(
        Osv, Osl, Wt, bu_v, bu_l, (float*)d_out);
}

// Round 5
// 257.106 us; speedup vs baseline: 1.1093x; 1.0282x over previous
//
#include <hip/hip_runtime.h>
#include <stdint.h>

// Problem constants
#define BB 16
#define T1C 512
#define T2C 64
#define DC 768
#define HC 12
#define EC 64
#define SC 576          // T1+T2
#define QSCALE 0.35355339059327379f   // 64^-0.25

typedef __attribute__((ext_vector_type(8))) short bf16x8;   // 8 bf16 = 4 VGPRs
typedef __attribute__((ext_vector_type(4))) float f32x4;    // MFMA C/D

// ---------- bf16 helpers ----------
__device__ __forceinline__ uint16_t f2b(float f) {          // RNE
    union { float f; uint32_t i; } v; v.f = f;
    return (uint16_t)((v.i + 0x7fffu + ((v.i >> 16) & 1u)) >> 16);
}
__device__ __forceinline__ uint16_t f2bfast(float f) {      // round-half-up (cheap)
    union { float f; uint32_t i; } v; v.f = f;
    return (uint16_t)((v.i + 0x8000u) >> 16);
}
__device__ __forceinline__ uint32_t pk2(float a, float b) {
    return (uint32_t)f2b(a) | ((uint32_t)f2b(b) << 16);
}

// async global->LDS, 16B per lane; LDS dest = wave-uniform base + lane*16
__device__ __forceinline__ void gll16(const void* g, void* l) {
    __builtin_amdgcn_global_load_lds(
        (const __attribute__((address_space(1))) uint32_t*)(uintptr_t)g,
        (__attribute__((address_space(3))) uint32_t*)(uintptr_t)l, 16, 0, 0);
}

#define WT_BLOCKS (24 * 24 * 14)   // 8064 wtrans blocks
#define XS_BLOCKS 3456             // 884736 chunks / 256

// ---------- fused prep: wtrans + xswz + detect in ONE launch ----------
// The three prep passes are mutually independent; fusing removes two launch
// bubbles and the full-device stall of the 1-block detect. detect is the
// LAST block (flags only read by attn, much later in the stream).
__global__ __launch_bounds__(256) void prep(
    const float* __restrict__ Wf, const float* __restrict__ Wi,
    const float* __restrict__ Wuv, const float* __restrict__ Wul,
    uint16_t* __restrict__ Wt,
    const float* __restrict__ Xf, const float* __restrict__ Xi,
    uint16_t* __restrict__ Of, uint16_t* __restrict__ Oi,
    const uint32_t* __restrict__ mw, int* __restrict__ flags)
{
    __shared__ union { float tile[32][33]; int d[3]; } sh;
    const int bid = blockIdx.x;
    if (bid < WT_BLOCKS) {
        // ---- weight transpose + f32->bf16: Wt[z][f][k] = W_z[k][f] ----
        const int z = bid / 576, r = bid % 576;
        const int kx = r % 24, fy = r / 24;
        const float* src = (z < 6)  ? Wf + (size_t)z * DC * DC
                         : (z < 12) ? Wi + (size_t)(z - 6) * DC * DC
                         : (z == 12 ? Wuv : Wul);
        uint16_t* dst = Wt + (size_t)z * DC * DC;
        const int tx = threadIdx.x & 31, ty = threadIdx.x >> 5;
        const int k0 = kx * 32, f0 = fy * 32;
#pragma unroll
        for (int q = 0; q < 4; q++)
            sh.tile[ty + q * 8][tx] = src[(size_t)(k0 + ty + q * 8) * DC + f0 + tx];
        __syncthreads();
#pragma unroll
        for (int q = 0; q < 4; q++)
            dst[(size_t)(f0 + ty + q * 8) * DC + k0 + tx] = f2b(sh.tile[tx][ty + q * 8]);
    } else if (bid < WT_BLOCKS + XS_BLOCKS) {
        // ---- X f32 -> bf16 swizzle (MFMA A-fragment order) ----
        // chunk cc: cc = ((p*24 + kt)*4 + qd)*16 + rlid holds
        // X[p*16+rlid][kt*32 + qd*8 .. +7]; frag load = 64 lanes x 16B burst.
        const int nf = BB * T1C * DC / 8;
        const int ni = BB * T2C * DC / 8;
        int t = (bid - WT_BLOCKS) * 256 + threadIdx.x;
        const float* src; uint16_t* dst; int cc;
        if (t < nf) { src = Xf; dst = Of; cc = t; }
        else        { cc = t - nf; if (cc >= ni) return; src = Xi; dst = Oi; }
        int rlid = cc & 15;
        int t2 = cc >> 4;
        int qd = t2 & 3;
        int t3 = t2 >> 2;
        int kt = t3 % 24;
        int p  = t3 / 24;
        const float* sp = src + (size_t)(p * 16 + rlid) * DC + kt * 32 + qd * 8;
        float4 a = *(const float4*)sp;
        float4 b = *(const float4*)(sp + 4);
        uint4 o;
        o.x = pk2(a.x, a.y); o.y = pk2(a.z, a.w);
        o.z = pk2(b.x, b.y); o.w = pk2(b.z, b.w);
        *(uint4*)(dst + (size_t)cc * 8) = o;
    } else {
        // ---- mask layout detect (deterministic -> graph-safe) ----
        if (threadIdx.x == 0) { sh.d[0] = 0; sh.d[1] = 0; sh.d[2] = 0; }
        __syncthreads();
        int lW = 0, lB = 0, lL = 0;
        for (int i = threadIdx.x; i < 2304; i += 256) {
            uint32_t w = mw[i];
            if (w > 1u) lW = 1;
            if (((w) & 0xffu) > 1u || ((w >> 8) & 0xffu) > 1u ||
                ((w >> 16) & 0xffu) > 1u || ((w >> 24) & 0xffu) > 1u) lB = 1;
            if ((w & 0xffffu) > 1u) lL = 1;
        }
        if (lW) atomicOr(&sh.d[0], 1);
        if (lB) atomicOr(&sh.d[1], 1);
        if (lL) atomicOr(&sh.d[2], 1);
        __syncthreads();
        if (threadIdx.x == 0)
            flags[0] = (!sh.d[0]) ? 0 : ((!sh.d[1]) ? 1 : (sh.d[2] ? 2 : 0));
    }
}

#define BSTR 76   // epilogue bounce stride (bf16 elems), conflict-free

// ---------- MFMA projection GEMM ----------
// R0 structure (128x128, 4 waves, small LDS, direct-global A-frags) with BOTH
// operands prefetched one full K-step ahead:
//  * B: double-buffered LDS (2 x 8KB), staged via gll16 one iter ahead (R4 win)
//  * A: register double-buffer af0/af1, issued one iter ahead (this round)
// Queue invariant at the per-step wait: [A(t)x4, S(t)x2, A(t+1)x4, S(t+1)x2];
// vmcnt(6) retires exactly A(t)+S(t), leaves the prefetch in flight -> every
// load gets a full-iteration (~700cy) latency window. Manual 2x unroll keeps
// all register-buffer indices static (no scratch).
__global__ __launch_bounds__(256, 3) void gemm_proj_mfma(
    const uint16_t* __restrict__ Xsf, const uint16_t* __restrict__ Xsi,
    const uint16_t* __restrict__ Wt,
    const float* __restrict__ b_f, const float* __restrict__ b_i,
    uint16_t* __restrict__ Pf, uint16_t* __restrict__ Pi)
{
    __shared__ union {
        uint16_t B[2][128 * 32];              // 16 KB double-buffered staging
        uint16_t bounce[4][16 * BSTR];        // 9.5 KB epilogue
    } sm;
    const int tid = threadIdx.x;
    const int w = tid >> 6, l = tid & 63;
    const bool isf = (blockIdx.x < 64);
    const int mx = isf ? blockIdx.x : blockIdx.x - 64;
    const int m0 = mx * 128;
    const int T  = isf ? T1C : T2C;
    const uint16_t* Xs = isf ? Xsf : Xsi;
    const float* bias  = isf ? b_f : b_i;
    uint16_t* P        = isf ? Pf : Pi;
    const int vmask    = isf ? 0x24 : 0x22;
    const int k6 = blockIdx.y / 6, nt = blockIdx.y % 6;
    const int n0 = nt * 128;
    const uint16_t* Bsrc = Wt + (size_t)((isf ? 0 : 6) + k6) * DC * DC;

    const int lid = l & 15, qd = l >> 4;
    const int wm = w >> 1, wn = w & 1;
    const int br = l >> 2, bk = (l & 3) * 8;
    const int p0 = mx * 8 + wm * 4;           // A panel base for this wave
    const int c0 = w * 2;                     // this wave's two staging chunks

    f32x4 acc[4][4] = {};
    bf16x8 af0[4], af1[4];

#define PJ_A(dst, t) { _Pragma("unroll") for (int i = 0; i < 4; i++) \
        dst[i] = *(const bf16x8*)(Xs + ((size_t)((p0 + i) * 24 + (t)) * 64 + l) * 8); }
#define PJ_S(bu, t) { _Pragma("unroll") for (int n = 0; n < 2; n++) \
        gll16(Bsrc + (size_t)(n0 + (c0 + n) * 16 + br) * DC + (t) * 32 + bk, \
              &sm.B[bu][(c0 + n) * 512]); }
#define PJ_C(bu, afc) { bf16x8 bq[4]; \
        _Pragma("unroll") for (int j = 0; j < 4; j++) \
            bq[j] = *(const bf16x8*)&sm.B[bu][(wn * 64 + j * 16 + lid) * 32 + qd * 8]; \
        _Pragma("unroll") for (int i = 0; i < 4; i++) \
        _Pragma("unroll") for (int j = 0; j < 4; j++) \
            acc[i][j] = __builtin_amdgcn_mfma_f32_16x16x32_bf16(afc[i], bq[j], acc[i][j], 0, 0, 0); }

    // prologue: A(0)+S(0) in flight
    PJ_A(af0, 0);
    PJ_S(0, 0);

    for (int k2 = 0; k2 < 12; ++k2) {
        // ---- even step kt = 2*k2: compute buf0/af0, prefetch kt+1 ----
        PJ_A(af1, 2 * k2 + 1);
        __builtin_amdgcn_s_barrier();          // all waves done reading B[1]
        __builtin_amdgcn_sched_barrier(0);
        PJ_S(1, 2 * k2 + 1);
        asm volatile("s_waitcnt vmcnt(6)" ::: "memory");   // A(kt)+S(kt) landed
        __builtin_amdgcn_sched_barrier(0);
        __builtin_amdgcn_s_barrier();          // publish B[0]
        __builtin_amdgcn_sched_barrier(0);
        PJ_C(0, af0);
        // ---- odd step kt = 2*k2+1: compute buf1/af1, prefetch kt+1 ----
        if (k2 < 11) { PJ_A(af0, 2 * k2 + 2); }
        __builtin_amdgcn_s_barrier();          // all waves done reading B[0]
        __builtin_amdgcn_sched_barrier(0);
        if (k2 < 11) {
            PJ_S(0, 2 * k2 + 2);
            asm volatile("s_waitcnt vmcnt(6)" ::: "memory");
        } else {
            asm volatile("s_waitcnt vmcnt(0)" ::: "memory");   // final drain
        }
        __builtin_amdgcn_sched_barrier(0);
        __builtin_amdgcn_s_barrier();          // publish B[1]
        __builtin_amdgcn_sched_barrier(0);
        PJ_C(1, af1);
    }
#undef PJ_A
#undef PJ_S
#undef PJ_C

    float bv[4];
#pragma unroll
    for (int j = 0; j < 4; j++)
        bv[j] = bias[k6 * DC + n0 + wn * 64 + j * 16 + lid];
    __syncthreads();   // all waves' K-loop LDS reads done before bounce overwrite

    uint16_t* reg = sm.bounce[w];
    const int mb = m0 + wm * 64;
    const int b = mb / T, tb = mb - b * T;     // 64-row wave tile never crosses b
    const int h = nt * 2 + wn;
    const int rrow = l >> 2;                   // readback row within pass
    const int rcol = (l & 3) * 16;             // readback col chunk

    if (!((vmask >> k6) & 1)) {
        // normal [t][e]: pass p = m-rows p*16..p*16+15 (i = p)
        uint16_t* dst0 = P + ((((size_t)k6 * BB + b) * HC + h) * T + tb + rrow) * EC + rcol;
#pragma unroll
        for (int p = 0; p < 4; p++) {
#pragma unroll
            for (int j = 0; j < 4; j++)
#pragma unroll
                for (int r = 0; r < 4; r++)
                    reg[(qd * 4 + r) * BSTR + j * 16 + lid] =
                        f2b((acc[p][j][r] + bv[j]) * QSCALE);
            uint4 d0 = *(const uint4*)&reg[rrow * BSTR + rcol];
            uint4 d1 = *(const uint4*)&reg[rrow * BSTR + rcol + 8];
            uint16_t* dst = dst0 + (size_t)p * 16 * EC;
            *(uint4*)dst = d0;
            *(uint4*)(dst + 8) = d1;
        }
    } else {
        // transposed [e][t]: pass p = e-rows p*16..p*16+15 (j = p)
        uint16_t* dst0 = P + (size_t)k6 * BB * HC * T * EC
                           + (((size_t)b * HC + h) * EC + rrow) * T + tb + rcol;
#pragma unroll
        for (int p = 0; p < 4; p++) {
#pragma unroll
            for (int i = 0; i < 4; i++) {
                uint32_t w0 = pk2((acc[i][p][0] + bv[p]) * QSCALE,
                                  (acc[i][p][1] + bv[p]) * QSCALE);
                uint32_t w1 = pk2((acc[i][p][2] + bv[p]) * QSCALE,
                                  (acc[i][p][3] + bv[p]) * QSCALE);
                *(uint2*)&reg[lid * BSTR + i * 16 + qd * 4] = make_uint2(w0, w1);
            }
            uint4 d0 = *(const uint4*)&reg[rrow * BSTR + rcol];
            uint4 d1 = *(const uint4*)&reg[rrow * BSTR + rcol + 8];
            uint16_t* dst = dst0 + (size_t)p * 16 * T;
            *(uint4*)dst = d0;
            *(uint4*)(dst + 8) = d1;
        }
    }
}

// ---------- MFMA output GEMM ----------
// Same double-prefetch transform as gemm_proj (A in regs + B in LDS, both
// one K-step ahead, vmcnt(6) steady-state).
__global__ __launch_bounds__(256, 3) void gemm_out_mfma(
    const uint16_t* __restrict__ Osv, const uint16_t* __restrict__ Osl,
    const uint16_t* __restrict__ Wt,
    const float* __restrict__ bu_v, const float* __restrict__ bu_l,
    float* __restrict__ out)
{
    __shared__ uint16_t Bs[2][128 * 32];
    const int tid = threadIdx.x;
    const int w = tid >> 6, l = tid & 63;
    const bool isv = (blockIdx.x < 64);
    const int mx = isv ? blockIdx.x : blockIdx.x - 64;
    const int m0 = mx * 128;
    const int rowoff = isv ? 0 : BB * T1C;
    const uint16_t* A = isv ? Osv : Osl;
    const uint16_t* Wtm = Wt + (size_t)(isv ? 12 : 13) * DC * DC;
    const float* bias = isv ? bu_v : bu_l;
    const int n0 = blockIdx.y * 128;
    const int lid = l & 15, qd = l >> 4;
    const int wm = w >> 1, wn = w & 1;
    const int br = l >> 2, bk = (l & 3) * 8;
    const int p0 = mx * 8 + wm * 4;
    const int c0 = w * 2;

    f32x4 acc[4][4] = {};
    bf16x8 af0[4], af1[4];

#define GO_A(dst, t) { _Pragma("unroll") for (int i = 0; i < 4; i++) \
        dst[i] = *(const bf16x8*)(A + ((size_t)((p0 + i) * 24 + (t)) * 64 + l) * 8); }
#define GO_S(bu, t) { _Pragma("unroll") for (int n = 0; n < 2; n++) \
        gll16(Wtm + (size_t)(n0 + (c0 + n) * 16 + br) * DC + (t) * 32 + bk, \
              &Bs[bu][(c0 + n) * 512]); }
#define GO_C(bu, afc) { bf16x8 bq[4]; \
        _Pragma("unroll") for (int j = 0; j < 4; j++) \
            bq[j] = *(const bf16x8*)&Bs[bu][(wn * 64 + j * 16 + lid) * 32 + qd * 8]; \
        _Pragma("unroll") for (int i = 0; i < 4; i++) \
        _Pragma("unroll") for (int j = 0; j < 4; j++) \
            acc[i][j] = __builtin_amdgcn_mfma_f32_16x16x32_bf16(afc[i], bq[j], acc[i][j], 0, 0, 0); }

    GO_A(af0, 0);
    GO_S(0, 0);

    for (int k2 = 0; k2 < 12; ++k2) {
        GO_A(af1, 2 * k2 + 1);
        __builtin_amdgcn_s_barrier();
        __builtin_amdgcn_sched_barrier(0);
        GO_S(1, 2 * k2 + 1);
        asm volatile("s_waitcnt vmcnt(6)" ::: "memory");
        __builtin_amdgcn_sched_barrier(0);
        __builtin_amdgcn_s_barrier();
        __builtin_amdgcn_sched_barrier(0);
        GO_C(0, af0);
        if (k2 < 11) { GO_A(af0, 2 * k2 + 2); }
        __builtin_amdgcn_s_barrier();
        __builtin_amdgcn_sched_barrier(0);
        if (k2 < 11) {
            GO_S(0, 2 * k2 + 2);
            asm volatile("s_waitcnt vmcnt(6)" ::: "memory");
        } else {
            asm volatile("s_waitcnt vmcnt(0)" ::: "memory");
        }
        __builtin_amdgcn_sched_barrier(0);
        __builtin_amdgcn_s_barrier();
        __builtin_amdgcn_sched_barrier(0);
        GO_C(1, af1);
    }
#undef GO_A
#undef GO_S
#undef GO_C

    float bv[4];
#pragma unroll
    for (int j = 0; j < 4; j++)
        bv[j] = bias[n0 + wn * 64 + j * 16 + lid];
#pragma unroll
    for (int i = 0; i < 4; i++)
#pragma unroll
        for (int j = 0; j < 4; j++)
#pragma unroll
            for (int r = 0; r < 4; r++) {
                int m = m0 + wm * 64 + i * 16 + qd * 4 + r;
                int f = n0 + wn * 64 + j * 16 + lid;
                out[(size_t)(rowoff + m) * DC + f] = acc[i][j][r] + bv[j];
            }
}

// ---------- MFMA flash attention: reg-prefetch double-buffered staging ----------
// grid (192 bh, 9 tiles): 192%8==0 => all 9 tiles of one bh map to the SAME
// XCD for K/V L2 reuse. Per chunk: issue chunk c+1's K/V global loads into
// regs BEFORE chunk c's barriers (T14 issue-early/write-late); ds_write chunk
// c's regs after a raw s_barrier; publish with lgkmcnt(0)+s_barrier.
__global__ __launch_bounds__(256, 3) void attn_mfma(
    const uint16_t* __restrict__ Pf,
    const uint16_t* __restrict__ Pi,
    const void* __restrict__ maskp,
    const int* __restrict__ flags,
    uint16_t* __restrict__ Osv,        // swizzled visual O (M=8192)
    uint16_t* __restrict__ Osl)        // swizzled language O (M=1024)
{
    __shared__ uint16_t Klds[64 * 72];      // [key][e]
    __shared__ uint16_t Vlds[64 * 72];      // [e][key]
    __shared__ uint16_t Plds[4][16 * 72];   // per-wave P [q][key]
    __shared__ float    Ma[SC];
    __shared__ float    Lw[4][16];

    const int bh = blockIdx.x;
    const int tile = blockIdx.y;
    const int b = bh / HC, h = bh % HC;
    const int tid = threadIdx.x;
    const int w = tid >> 6, l = tid & 63;
    const int lid = l & 15, qd = l >> 4;

    const size_t SF = (size_t)BB * HC * T1C * EC;
    const size_t SI = (size_t)BB * HC * T2C * EC;

    const bool vis = (tile < 8);
    const uint16_t *Qa, *Qb, *K1, *K2, *V1, *V2;
    uint16_t* O; int Tq, q0;
    if (vis) { Qa = Pf + 1 * SF; Qb = Pf + 3 * SF; K1 = Pf;          K2 = Pi;
               V1 = Pf + 2 * SF; V2 = Pi + 1 * SI; O = Osv; Tq = T1C; q0 = tile * 64; }
    else     { Qa = Pi + 2 * SI; Qb = Pi + 3 * SI; K1 = Pf + 4 * SF; K2 = Pi + 4 * SI;
               V1 = Pf + 5 * SF; V2 = Pi + 5 * SI; O = Osl; Tq = T2C; q0 = 0; }

    {
        const int kind = flags[0];
        for (int i = tid; i < SC; i += 256) {
            int idx = b * SC + i;
            int mv;
            if (kind == 0)      mv = ((const uint32_t*)maskp)[idx] != 0u;
            else if (kind == 1) mv = ((const uint8_t*)maskp)[idx] != 0;
            else                mv = ((const uint16_t*)maskp)[idx] != 0;
            Ma[i] = mv ? -1e9f : 0.0f;
        }
    }

    // preload BOTH Q variants (the 9th chunk switches query matrix)
    const int q = q0 + w * 16 + lid;
    const uint16_t* Qrow  = Qa + ((size_t)bh * Tq + q) * EC;
    const uint16_t* Qrow2 = Qb + ((size_t)bh * Tq + q) * EC;
    bf16x8 qf0 = *(const bf16x8*)(Qrow + qd * 8);
    bf16x8 qf1 = *(const bf16x8*)(Qrow + 32 + qd * 8);
    bf16x8 qg0 = *(const bf16x8*)(Qrow2 + qd * 8);
    bf16x8 qg1 = *(const bf16x8*)(Qrow2 + 32 + qd * 8);

    f32x4 o[4];
#pragma unroll
    for (int ef = 0; ef < 4; ef++) { o[ef][0]=0.f; o[ef][1]=0.f; o[ef][2]=0.f; o[ef][3]=0.f; }
    float u[4] = {0.f, 0.f, 0.f, 0.f};

    const int skey = tid >> 2, se0 = (tid & 3) * 16;   // K stage (row, col chunk)
    const int ve = tid >> 2,  vc = tid & 3;            // V stage (e-row, key chunk)

    // chunk-c staging source addresses (c compile-time under full unroll)
    auto kptr = [&](int c) -> const uint16_t* {
        return (c < 8) ? K1 + ((size_t)bh * T1C + c * 64 + skey) * EC + se0
                       : K2 + ((size_t)bh * T2C + skey) * EC + se0;
    };
    auto vptr = [&](int c) -> const uint16_t* {
        return (c < 8) ? V1 + ((size_t)bh * EC + ve) * T1C + c * 64 + vc * 16
                       : V2 + ((size_t)bh * EC + ve) * T2C + vc * 16;
    };

    // prologue: issue chunk 0 loads into current regs
    uint4 ka0 = *(const uint4*)kptr(0);
    uint4 ka1 = *(const uint4*)(kptr(0) + 8);
    uint4 va0 = *(const uint4*)vptr(0);
    uint4 va1 = *(const uint4*)(vptr(0) + 8);

#pragma unroll
    for (int c = 0; c < 9; ++c) {
        // issue next chunk's loads FIRST (newer in vmcnt order; the compiler's
        // auto-wait before the ds_writes below then only drains chunk c's loads)
        uint4 kb0, kb1, vb0, vb1;
        if (c < 8) {
            kb0 = *(const uint4*)kptr(c + 1);
            kb1 = *(const uint4*)(kptr(c + 1) + 8);
            vb0 = *(const uint4*)vptr(c + 1);
            vb1 = *(const uint4*)(vptr(c + 1) + 8);
        }
        __builtin_amdgcn_s_barrier();              // prev chunk LDS reads done
        __builtin_amdgcn_sched_barrier(0);
        *(uint4*)&Klds[skey * 72 + se0]         = ka0;
        *(uint4*)&Klds[skey * 72 + se0 + 8]     = ka1;
        *(uint4*)&Vlds[ve * 72 + vc * 16]       = va0;
        *(uint4*)&Vlds[ve * 72 + vc * 16 + 8]   = va1;
        asm volatile("s_waitcnt lgkmcnt(0)" ::: "memory");
        __builtin_amdgcn_sched_barrier(0);
        __builtin_amdgcn_s_barrier();              // publish K/V (and Ma @c=0)
        __builtin_amdgcn_sched_barrier(0);

        const int k0 = c * 64;
        const bf16x8 q_0 = (c < 8) ? qf0 : qg0;
        const bf16x8 q_1 = (c < 8) ? qf1 : qg1;
        // QK^T: D[q][key]
        f32x4 s[4];
#pragma unroll
        for (int sub = 0; sub < 4; sub++) {
            bf16x8 kf0 = *(const bf16x8*)&Klds[(sub * 16 + lid) * 72 + qd * 8];
            bf16x8 kf1 = *(const bf16x8*)&Klds[(sub * 16 + lid) * 72 + 32 + qd * 8];
            f32x4 z; z[0]=0.f; z[1]=0.f; z[2]=0.f; z[3]=0.f;
            z = __builtin_amdgcn_mfma_f32_16x16x32_bf16(q_0, kf0, z, 0, 0, 0);
            s[sub] = __builtin_amdgcn_mfma_f32_16x16x32_bf16(q_1, kf1, z, 0, 0, 0);
        }
        // p = exp(s + mask); accumulate row-sum; write P (C-layout -> [q][key])
#pragma unroll
        for (int sub = 0; sub < 4; sub++) {
            float mv = Ma[k0 + sub * 16 + lid];
#pragma unroll
            for (int r = 0; r < 4; r++) {
                float p = __expf(s[sub][r] + mv);
                u[r] += p;
                Plds[w][(qd * 4 + r) * 72 + sub * 16 + lid] = f2bfast(p);
            }
        }
        // PV as O^T = Vt * P^T (wave-local Plds round trip, no barrier)
#pragma unroll
        for (int half = 0; half < 2; half++) {
            bf16x8 pf = *(const bf16x8*)&Plds[w][lid * 72 + half * 32 + qd * 8];
#pragma unroll
            for (int ef = 0; ef < 4; ef++) {
                bf16x8 vf = *(const bf16x8*)&Vlds[(ef * 16 + lid) * 72 + half * 32 + qd * 8];
                o[ef] = __builtin_amdgcn_mfma_f32_16x16x32_bf16(vf, pf, o[ef], 0, 0, 0);
            }
        }
        if (c < 8) { ka0 = kb0; ka1 = kb1; va0 = vb0; va1 = vb1; }
    }

    // one-time row-sum reduction across key-lanes (bits 0-3)
#pragma unroll
    for (int d = 1; d <= 8; d <<= 1)
#pragma unroll
        for (int r = 0; r < 4; r++)
            u[r] += __shfl_xor(u[r], d, 64);
    if (lid == 0) {
#pragma unroll
        for (int r = 0; r < 4; r++) Lw[w][qd * 4 + r] = u[r];
    }
    float rl = 1.f / Lw[w][lid];   // l for this lane's query (wave-local ordering)

    // O write in gemm_out's swizzled A-frag order:
    // m = b*Tq + q; panel p = m>>4 (wave-uniform), rlid = lid.
    // col = h*64 + e, e = ef*16 + qd*4 + r  ->  kt = h*2 + (ef>>1),
    // cq = (ef&1)*2 + (qd>>1), j = (qd&1)*4 + r  -> one 8B store per ef.
    const size_t p = ((size_t)b * Tq + q0 + w * 16) >> 4;
#pragma unroll
    for (int ef = 0; ef < 4; ef++) {
        uint32_t w0 = pk2(o[ef][0] * rl, o[ef][1] * rl);
        uint32_t w1 = pk2(o[ef][2] * rl, o[ef][3] * rl);
        size_t chunk = ((p * 24 + h * 2 + (ef >> 1)) * 4 + (ef & 1) * 2 + (qd >> 1)) * 16 + lid;
        *(uint2*)(O + chunk * 8 + (qd & 1) * 4) = make_uint2(w0, w1);
    }
}

// ---------- launch ----------
extern "C" void kernel_launch(void* const* d_in, const int* in_sizes, int n_in,
                              void* d_out, int out_size, void* d_ws, size_t ws_size,
                              hipStream_t stream)
{
    const float* feats = (const float*)d_in[0];
    const float* inps  = (const float*)d_in[1];
    const void*  maskp = d_in[2];
    const float* W_f   = (const float*)d_in[3];
    const float* b_f   = (const float*)d_in[4];
    const float* W_i   = (const float*)d_in[5];
    const float* b_i   = (const float*)d_in[6];
    const float* Wu_v  = (const float*)d_in[7];
    const float* bu_v  = (const float*)d_in[8];
    const float* Wu_l  = (const float*)d_in[9];
    const float* bu_l  = (const float*)d_in[10];

    const size_t MAT = (size_t)DC * DC;               // 589824
    const size_t PF_E = 6ull * BB * HC * T1C * EC;
    const size_t PI_E = 6ull * BB * HC * T2C * EC;
    uint16_t* Wt  = (uint16_t*)d_ws;
    uint16_t* Osv = Wt;                               // reuses dead Wt[0..11]
    uint16_t* Osl = Wt + (size_t)BB * T1C * HC * EC;
    uint16_t* Pf  = Wt + 14 * MAT;
    uint16_t* Pi  = Pf + PF_E;
    int* flags    = (int*)(Pi + PI_E);

    // Swizzled bf16 X lives in d_out's first ~21 MB: d_out is only written by
    // the final gemm_out launch (stream-ordered after all Xs reads).
    uint16_t* Xsf = (uint16_t*)d_out;
    uint16_t* Xsi = Xsf + (size_t)BB * T1C * DC;

    prep<<<dim3(WT_BLOCKS + XS_BLOCKS + 1), dim3(256), 0, stream>>>(
        W_f, W_i, Wu_v, Wu_l, Wt, feats, inps, Xsf, Xsi,
        (const uint32_t*)maskp, flags);

    gemm_proj_mfma<<<dim3(72, 36), dim3(256), 0, stream>>>(
        Xsf, Xsi, Wt, b_f, b_i, Pf, Pi);

    attn_mfma<<<dim3(BB * HC, 9), dim3(256), 0, stream>>>(
        Pf, Pi, maskp, flags, Osv, Osl);

    gemm_out_mfma<<<dim3(72, 6), dim3(256), 0, stream>>>(
        Osv, Osl, Wt, bu_v, bu_l, (float*)d_out);
}

// Round 6
// 254.926 us; speedup vs baseline: 1.1188x; 1.0086x over previous
//
#include <hip/hip_runtime.h>
#include <stdint.h>

// Problem constants
#define BB 16
#define T1C 512
#define T2C 64
#define DC 768
#define HC 12
#define EC 64
#define SC 576          // T1+T2
#define QSCALE 0.35355339059327379f   // 64^-0.25

typedef __attribute__((ext_vector_type(8))) short bf16x8;   // 8 bf16 = 4 VGPRs
typedef __attribute__((ext_vector_type(4))) float f32x4;    // MFMA C/D

// ---------- bf16 helpers ----------
__device__ __forceinline__ uint16_t f2b(float f) {          // RNE
    union { float f; uint32_t i; } v; v.f = f;
    return (uint16_t)((v.i + 0x7fffu + ((v.i >> 16) & 1u)) >> 16);
}
__device__ __forceinline__ uint16_t f2bfast(float f) {      // round-half-up (cheap)
    union { float f; uint32_t i; } v; v.f = f;
    return (uint16_t)((v.i + 0x8000u) >> 16);
}
__device__ __forceinline__ uint32_t pk2(float a, float b) {
    return (uint32_t)f2b(a) | ((uint32_t)f2b(b) << 16);
}

// async global->LDS, 16B per lane; LDS dest = wave-uniform base + lane*16
__device__ __forceinline__ void gll16(const void* g, void* l) {
    __builtin_amdgcn_global_load_lds(
        (const __attribute__((address_space(1))) uint32_t*)(uintptr_t)g,
        (__attribute__((address_space(3))) uint32_t*)(uintptr_t)l, 16, 0, 0);
}

#define WT_BLOCKS (24 * 24 * 14)   // 8064 wtrans blocks
#define XS_BLOCKS 3456             // 884736 chunks / 256

// ---------- fused prep: wtrans + xswz + detect in ONE launch ----------
__global__ __launch_bounds__(256) void prep(
    const float* __restrict__ Wf, const float* __restrict__ Wi,
    const float* __restrict__ Wuv, const float* __restrict__ Wul,
    uint16_t* __restrict__ Wt,
    const float* __restrict__ Xf, const float* __restrict__ Xi,
    uint16_t* __restrict__ Of, uint16_t* __restrict__ Oi,
    const uint32_t* __restrict__ mw, int* __restrict__ flags)
{
    __shared__ union { float tile[32][33]; int d[3]; } sh;
    const int bid = blockIdx.x;
    if (bid < WT_BLOCKS) {
        // ---- weight transpose + f32->bf16: Wt[z][f][k] = W_z[k][f] ----
        const int z = bid / 576, r = bid % 576;
        const int kx = r % 24, fy = r / 24;
        const float* src = (z < 6)  ? Wf + (size_t)z * DC * DC
                         : (z < 12) ? Wi + (size_t)(z - 6) * DC * DC
                         : (z == 12 ? Wuv : Wul);
        uint16_t* dst = Wt + (size_t)z * DC * DC;
        const int tx = threadIdx.x & 31, ty = threadIdx.x >> 5;
        const int k0 = kx * 32, f0 = fy * 32;
#pragma unroll
        for (int q = 0; q < 4; q++)
            sh.tile[ty + q * 8][tx] = src[(size_t)(k0 + ty + q * 8) * DC + f0 + tx];
        __syncthreads();
#pragma unroll
        for (int q = 0; q < 4; q++)
            dst[(size_t)(f0 + ty + q * 8) * DC + k0 + tx] = f2b(sh.tile[tx][ty + q * 8]);
    } else if (bid < WT_BLOCKS + XS_BLOCKS) {
        // ---- X f32 -> bf16 swizzle (MFMA A-fragment order) ----
        // chunk cc = ((p*24 + kt)*4 + qd)*16 + rlid holds
        // X[p*16+rlid][kt*32 + qd*8 .. +7]; frag/stage = 64 lanes x 16B burst.
        const int nf = BB * T1C * DC / 8;
        const int ni = BB * T2C * DC / 8;
        int t = (bid - WT_BLOCKS) * 256 + threadIdx.x;
        const float* src; uint16_t* dst; int cc;
        if (t < nf) { src = Xf; dst = Of; cc = t; }
        else        { cc = t - nf; if (cc >= ni) return; src = Xi; dst = Oi; }
        int rlid = cc & 15;
        int t2 = cc >> 4;
        int qd = t2 & 3;
        int t3 = t2 >> 2;
        int kt = t3 % 24;
        int p  = t3 / 24;
        const float* sp = src + (size_t)(p * 16 + rlid) * DC + kt * 32 + qd * 8;
        float4 a = *(const float4*)sp;
        float4 b = *(const float4*)(sp + 4);
        uint4 o;
        o.x = pk2(a.x, a.y); o.y = pk2(a.z, a.w);
        o.z = pk2(b.x, b.y); o.w = pk2(b.z, b.w);
        *(uint4*)(dst + (size_t)cc * 8) = o;
    } else {
        // ---- mask layout detect (deterministic -> graph-safe) ----
        if (threadIdx.x == 0) { sh.d[0] = 0; sh.d[1] = 0; sh.d[2] = 0; }
        __syncthreads();
        int lW = 0, lB = 0, lL = 0;
        for (int i = threadIdx.x; i < 2304; i += 256) {
            uint32_t w = mw[i];
            if (w > 1u) lW = 1;
            if (((w) & 0xffu) > 1u || ((w >> 8) & 0xffu) > 1u ||
                ((w >> 16) & 0xffu) > 1u || ((w >> 24) & 0xffu) > 1u) lB = 1;
            if ((w & 0xffffu) > 1u) lL = 1;
        }
        if (lW) atomicOr(&sh.d[0], 1);
        if (lB) atomicOr(&sh.d[1], 1);
        if (lL) atomicOr(&sh.d[2], 1);
        __syncthreads();
        if (threadIdx.x == 0)
            flags[0] = (!sh.d[0]) ? 0 : ((!sh.d[1]) ? 1 : (sh.d[2] ? 2 : 0));
    }
}

#define BSTR 76   // epilogue bounce stride (bf16 elems), conflict-free

// ---------- MFMA projection GEMM: BOTH operands gll16-staged (m97 pattern) ----------
// 128x128 tile, 4 waves, BK=32, double-buffered A+B in LDS (32 KB total).
// Per step t: barrier#1 (all waves done reading buf nb) -> stage(t+1) into nb
// (2 A + 2 B gll16/wave) -> vmcnt(4): retires own stage(t) issued LAST step
// (full ~500cy window), leaves stage(t+1) in flight -> barrier#2 publishes ->
// ds_read frags + 16 MFMA. A staged ONCE per block (was 2x per-wave global),
// fewer address VGPRs than R4/R5 -> fits the (256,4) 64-VGPR cap.
__global__ __launch_bounds__(256, 4) void gemm_proj_mfma(
    const uint16_t* __restrict__ Xsf, const uint16_t* __restrict__ Xsi,
    const uint16_t* __restrict__ Wt,
    const float* __restrict__ b_f, const float* __restrict__ b_i,
    uint16_t* __restrict__ Pf, uint16_t* __restrict__ Pi)
{
    __shared__ union {
        struct { uint16_t A[2][128 * 32]; uint16_t B[2][128 * 32]; } st; // 32 KB
        uint16_t bounce[4][16 * BSTR];        // 9.5 KB epilogue
    } sm;
    const int tid = threadIdx.x;
    const int w = tid >> 6, l = tid & 63;
    const bool isf = (blockIdx.x < 64);
    const int mx = isf ? blockIdx.x : blockIdx.x - 64;
    const int m0 = mx * 128;
    const int T  = isf ? T1C : T2C;
    const uint16_t* Xs = isf ? Xsf : Xsi;
    const float* bias  = isf ? b_f : b_i;
    uint16_t* P        = isf ? Pf : Pi;
    const int vmask    = isf ? 0x24 : 0x22;
    const int k6 = blockIdx.y / 6, nt = blockIdx.y % 6;
    const int n0 = nt * 128;
    const uint16_t* Bsrc = Wt + (size_t)((isf ? 0 : 6) + k6) * DC * DC;

    const int lid = l & 15, qd = l >> 4;
    const int wm = w >> 1, wn = w & 1;
    const int br = l >> 2, bk = (l & 3) * 8;
    const int c0 = w * 2;                     // this wave's 2 A-segments / B-chunks

    f32x4 acc[4][4] = {};

    // stage tile t into buffer bu: A segments c0,c0+1 (panels mx*8+c0..) +
    // B chunks c0,c0+1. Each gll16 = 64 lanes x 16B = 1KB contiguous.
#define PJ_S(bu, t) { \
        _Pragma("unroll") for (int n = 0; n < 2; n++) \
            gll16(Xs + ((size_t)((mx * 8 + c0 + n) * 24 + (t)) * 64 + l) * 8, \
                  &sm.st.A[bu][(c0 + n) * 512]); \
        _Pragma("unroll") for (int n = 0; n < 2; n++) \
            gll16(Bsrc + (size_t)(n0 + (c0 + n) * 16 + br) * DC + (t) * 32 + bk, \
                  &sm.st.B[bu][(c0 + n) * 512]); }
#define PJ_C(bu) { bf16x8 aq[4], bq[4]; \
        _Pragma("unroll") for (int i = 0; i < 4; i++) \
            aq[i] = *(const bf16x8*)&sm.st.A[bu][((wm * 4 + i) * 64 + l) * 8]; \
        _Pragma("unroll") for (int j = 0; j < 4; j++) \
            bq[j] = *(const bf16x8*)&sm.st.B[bu][(wn * 64 + j * 16 + lid) * 32 + qd * 8]; \
        _Pragma("unroll") for (int i = 0; i < 4; i++) \
        _Pragma("unroll") for (int j = 0; j < 4; j++) \
            acc[i][j] = __builtin_amdgcn_mfma_f32_16x16x32_bf16(aq[i], bq[j], acc[i][j], 0, 0, 0); }

    PJ_S(0, 0);                                // prologue: tile 0 in flight (4)

    for (int kt = 0; kt < DC / 32; ++kt) {
        const int cb = kt & 1, nb = cb ^ 1;
        __builtin_amdgcn_s_barrier();          // all waves done reading buf nb
        __builtin_amdgcn_sched_barrier(0);
        if (kt < 23) {
            PJ_S(nb, kt + 1);                  // outstanding: S(t)4 + S(t+1)4
            asm volatile("s_waitcnt vmcnt(4)" ::: "memory");  // retire S(t)
        } else {
            asm volatile("s_waitcnt vmcnt(0)" ::: "memory");  // final drain
        }
        __builtin_amdgcn_sched_barrier(0);
        __builtin_amdgcn_s_barrier();          // publish tile kt cross-wave
        __builtin_amdgcn_sched_barrier(0);
        PJ_C(cb);
    }
#undef PJ_S
#undef PJ_C

    float bv[4];
#pragma unroll
    for (int j = 0; j < 4; j++)
        bv[j] = bias[k6 * DC + n0 + wn * 64 + j * 16 + lid];
    __syncthreads();   // all waves' K-loop LDS reads done before bounce overwrite

    uint16_t* reg = sm.bounce[w];
    const int mb = m0 + wm * 64;
    const int b = mb / T, tb = mb - b * T;     // 64-row wave tile never crosses b
    const int h = nt * 2 + wn;
    const int rrow = l >> 2;                   // readback row within pass
    const int rcol = (l & 3) * 16;             // readback col chunk

    if (!((vmask >> k6) & 1)) {
        // normal [t][e]: pass p = m-rows p*16..p*16+15 (i = p)
        uint16_t* dst0 = P + ((((size_t)k6 * BB + b) * HC + h) * T + tb + rrow) * EC + rcol;
#pragma unroll
        for (int p = 0; p < 4; p++) {
#pragma unroll
            for (int j = 0; j < 4; j++)
#pragma unroll
                for (int r = 0; r < 4; r++)
                    reg[(qd * 4 + r) * BSTR + j * 16 + lid] =
                        f2b((acc[p][j][r] + bv[j]) * QSCALE);
            uint4 d0 = *(const uint4*)&reg[rrow * BSTR + rcol];
            uint4 d1 = *(const uint4*)&reg[rrow * BSTR + rcol + 8];
            uint16_t* dst = dst0 + (size_t)p * 16 * EC;
            *(uint4*)dst = d0;
            *(uint4*)(dst + 8) = d1;
        }
    } else {
        // transposed [e][t]: pass p = e-rows p*16..p*16+15 (j = p)
        uint16_t* dst0 = P + (size_t)k6 * BB * HC * T * EC
                           + (((size_t)b * HC + h) * EC + rrow) * T + tb + rcol;
#pragma unroll
        for (int p = 0; p < 4; p++) {
#pragma unroll
            for (int i = 0; i < 4; i++) {
                uint32_t w0 = pk2((acc[i][p][0] + bv[p]) * QSCALE,
                                  (acc[i][p][1] + bv[p]) * QSCALE);
                uint32_t w1 = pk2((acc[i][p][2] + bv[p]) * QSCALE,
                                  (acc[i][p][3] + bv[p]) * QSCALE);
                *(uint2*)&reg[lid * BSTR + i * 16 + qd * 4] = make_uint2(w0, w1);
            }
            uint4 d0 = *(const uint4*)&reg[rrow * BSTR + rcol];
            uint4 d1 = *(const uint4*)&reg[rrow * BSTR + rcol + 8];
            uint16_t* dst = dst0 + (size_t)p * 16 * T;
            *(uint4*)dst = d0;
            *(uint4*)(dst + 8) = d1;
        }
    }
}

// ---------- MFMA output GEMM: same both-staged schedule ----------
__global__ __launch_bounds__(256, 4) void gemm_out_mfma(
    const uint16_t* __restrict__ Osv, const uint16_t* __restrict__ Osl,
    const uint16_t* __restrict__ Wt,
    const float* __restrict__ bu_v, const float* __restrict__ bu_l,
    float* __restrict__ out)
{
    __shared__ struct { uint16_t A[2][128 * 32]; uint16_t B[2][128 * 32]; } st;
    const int tid = threadIdx.x;
    const int w = tid >> 6, l = tid & 63;
    const bool isv = (blockIdx.x < 64);
    const int mx = isv ? blockIdx.x : blockIdx.x - 64;
    const int m0 = mx * 128;
    const int rowoff = isv ? 0 : BB * T1C;
    const uint16_t* A = isv ? Osv : Osl;
    const uint16_t* Wtm = Wt + (size_t)(isv ? 12 : 13) * DC * DC;
    const float* bias = isv ? bu_v : bu_l;
    const int n0 = blockIdx.y * 128;
    const int lid = l & 15, qd = l >> 4;
    const int wm = w >> 1, wn = w & 1;
    const int br = l >> 2, bk = (l & 3) * 8;
    const int c0 = w * 2;

    f32x4 acc[4][4] = {};

#define GO_S(bu, t) { \
        _Pragma("unroll") for (int n = 0; n < 2; n++) \
            gll16(A + ((size_t)((mx * 8 + c0 + n) * 24 + (t)) * 64 + l) * 8, \
                  &st.A[bu][(c0 + n) * 512]); \
        _Pragma("unroll") for (int n = 0; n < 2; n++) \
            gll16(Wtm + (size_t)(n0 + (c0 + n) * 16 + br) * DC + (t) * 32 + bk, \
                  &st.B[bu][(c0 + n) * 512]); }
#define GO_C(bu) { bf16x8 aq[4], bq[4]; \
        _Pragma("unroll") for (int i = 0; i < 4; i++) \
            aq[i] = *(const bf16x8*)&st.A[bu][((wm * 4 + i) * 64 + l) * 8]; \
        _Pragma("unroll") for (int j = 0; j < 4; j++) \
            bq[j] = *(const bf16x8*)&st.B[bu][(wn * 64 + j * 16 + lid) * 32 + qd * 8]; \
        _Pragma("unroll") for (int i = 0; i < 4; i++) \
        _Pragma("unroll") for (int j = 0; j < 4; j++) \
            acc[i][j] = __builtin_amdgcn_mfma_f32_16x16x32_bf16(aq[i], bq[j], acc[i][j], 0, 0, 0); }

    GO_S(0, 0);

    for (int kt = 0; kt < DC / 32; ++kt) {
        const int cb = kt & 1, nb = cb ^ 1;
        __builtin_amdgcn_s_barrier();
        __builtin_amdgcn_sched_barrier(0);
        if (kt < 23) {
            GO_S(nb, kt + 1);
            asm volatile("s_waitcnt vmcnt(4)" ::: "memory");
        } else {
            asm volatile("s_waitcnt vmcnt(0)" ::: "memory");
        }
        __builtin_amdgcn_sched_barrier(0);
        __builtin_amdgcn_s_barrier();
        __builtin_amdgcn_sched_barrier(0);
        GO_C(cb);
    }
#undef GO_S
#undef GO_C

    float bv[4];
#pragma unroll
    for (int j = 0; j < 4; j++)
        bv[j] = bias[n0 + wn * 64 + j * 16 + lid];
#pragma unroll
    for (int i = 0; i < 4; i++)
#pragma unroll
        for (int j = 0; j < 4; j++)
#pragma unroll
            for (int r = 0; r < 4; r++) {
                int m = m0 + wm * 64 + i * 16 + qd * 4 + r;
                int f = n0 + wn * 64 + j * 16 + lid;
                out[(size_t)(rowoff + m) * DC + f] = acc[i][j][r] + bv[j];
            }
}

// ---------- MFMA flash attention: reg-prefetch double-buffered staging ----------
// grid (192 bh, 9 tiles): 192%8==0 => all 9 tiles of one bh map to the SAME
// XCD for K/V L2 reuse. Per chunk: issue chunk c+1's K/V global loads into
// regs BEFORE chunk c's barriers (T14 issue-early/write-late); ds_write chunk
// c's regs after a raw s_barrier; publish with lgkmcnt(0)+s_barrier.
__global__ __launch_bounds__(256, 3) void attn_mfma(
    const uint16_t* __restrict__ Pf,
    const uint16_t* __restrict__ Pi,
    const void* __restrict__ maskp,
    const int* __restrict__ flags,
    uint16_t* __restrict__ Osv,        // swizzled visual O (M=8192)
    uint16_t* __restrict__ Osl)        // swizzled language O (M=1024)
{
    __shared__ uint16_t Klds[64 * 72];      // [key][e]
    __shared__ uint16_t Vlds[64 * 72];      // [e][key]
    __shared__ uint16_t Plds[4][16 * 72];   // per-wave P [q][key]
    __shared__ float    Ma[SC];
    __shared__ float    Lw[4][16];

    const int bh = blockIdx.x;
    const int tile = blockIdx.y;
    const int b = bh / HC, h = bh % HC;
    const int tid = threadIdx.x;
    const int w = tid >> 6, l = tid & 63;
    const int lid = l & 15, qd = l >> 4;

    const size_t SF = (size_t)BB * HC * T1C * EC;
    const size_t SI = (size_t)BB * HC * T2C * EC;

    const bool vis = (tile < 8);
    const uint16_t *Qa, *Qb, *K1, *K2, *V1, *V2;
    uint16_t* O; int Tq, q0;
    if (vis) { Qa = Pf + 1 * SF; Qb = Pf + 3 * SF; K1 = Pf;          K2 = Pi;
               V1 = Pf + 2 * SF; V2 = Pi + 1 * SI; O = Osv; Tq = T1C; q0 = tile * 64; }
    else     { Qa = Pi + 2 * SI; Qb = Pi + 3 * SI; K1 = Pf + 4 * SF; K2 = Pi + 4 * SI;
               V1 = Pf + 5 * SF; V2 = Pi + 5 * SI; O = Osl; Tq = T2C; q0 = 0; }

    {
        const int kind = flags[0];
        for (int i = tid; i < SC; i += 256) {
            int idx = b * SC + i;
            int mv;
            if (kind == 0)      mv = ((const uint32_t*)maskp)[idx] != 0u;
            else if (kind == 1) mv = ((const uint8_t*)maskp)[idx] != 0;
            else                mv = ((const uint16_t*)maskp)[idx] != 0;
            Ma[i] = mv ? -1e9f : 0.0f;
        }
    }

    // preload BOTH Q variants (the 9th chunk switches query matrix)
    const int q = q0 + w * 16 + lid;
    const uint16_t* Qrow  = Qa + ((size_t)bh * Tq + q) * EC;
    const uint16_t* Qrow2 = Qb + ((size_t)bh * Tq + q) * EC;
    bf16x8 qf0 = *(const bf16x8*)(Qrow + qd * 8);
    bf16x8 qf1 = *(const bf16x8*)(Qrow + 32 + qd * 8);
    bf16x8 qg0 = *(const bf16x8*)(Qrow2 + qd * 8);
    bf16x8 qg1 = *(const bf16x8*)(Qrow2 + 32 + qd * 8);

    f32x4 o[4];
#pragma unroll
    for (int ef = 0; ef < 4; ef++) { o[ef][0]=0.f; o[ef][1]=0.f; o[ef][2]=0.f; o[ef][3]=0.f; }
    float u[4] = {0.f, 0.f, 0.f, 0.f};

    const int skey = tid >> 2, se0 = (tid & 3) * 16;   // K stage (row, col chunk)
    const int ve = tid >> 2,  vc = tid & 3;            // V stage (e-row, key chunk)

    // chunk-c staging source addresses (c compile-time under full unroll)
    auto kptr = [&](int c) -> const uint16_t* {
        return (c < 8) ? K1 + ((size_t)bh * T1C + c * 64 + skey) * EC + se0
                       : K2 + ((size_t)bh * T2C + skey) * EC + se0;
    };
    auto vptr = [&](int c) -> const uint16_t* {
        return (c < 8) ? V1 + ((size_t)bh * EC + ve) * T1C + c * 64 + vc * 16
                       : V2 + ((size_t)bh * EC + ve) * T2C + vc * 16;
    };

    // prologue: issue chunk 0 loads into current regs
    uint4 ka0 = *(const uint4*)kptr(0);
    uint4 ka1 = *(const uint4*)(kptr(0) + 8);
    uint4 va0 = *(const uint4*)vptr(0);
    uint4 va1 = *(const uint4*)(vptr(0) + 8);

#pragma unroll
    for (int c = 0; c < 9; ++c) {
        // issue next chunk's loads FIRST (newer in vmcnt order; the compiler's
        // auto-wait before the ds_writes below then only drains chunk c's loads)
        uint4 kb0, kb1, vb0, vb1;
        if (c < 8) {
            kb0 = *(const uint4*)kptr(c + 1);
            kb1 = *(const uint4*)(kptr(c + 1) + 8);
            vb0 = *(const uint4*)vptr(c + 1);
            vb1 = *(const uint4*)(vptr(c + 1) + 8);
        }
        __builtin_amdgcn_s_barrier();              // prev chunk LDS reads done
        __builtin_amdgcn_sched_barrier(0);
        *(uint4*)&Klds[skey * 72 + se0]         = ka0;
        *(uint4*)&Klds[skey * 72 + se0 + 8]     = ka1;
        *(uint4*)&Vlds[ve * 72 + vc * 16]       = va0;
        *(uint4*)&Vlds[ve * 72 + vc * 16 + 8]   = va1;
        asm volatile("s_waitcnt lgkmcnt(0)" ::: "memory");
        __builtin_amdgcn_sched_barrier(0);
        __builtin_amdgcn_s_barrier();              // publish K/V (and Ma @c=0)
        __builtin_amdgcn_sched_barrier(0);

        const int k0 = c * 64;
        const bf16x8 q_0 = (c < 8) ? qf0 : qg0;
        const bf16x8 q_1 = (c < 8) ? qf1 : qg1;
        // QK^T: D[q][key]
        f32x4 s[4];
#pragma unroll
        for (int sub = 0; sub < 4; sub++) {
            bf16x8 kf0 = *(const bf16x8*)&Klds[(sub * 16 + lid) * 72 + qd * 8];
            bf16x8 kf1 = *(const bf16x8*)&Klds[(sub * 16 + lid) * 72 + 32 + qd * 8];
            f32x4 z; z[0]=0.f; z[1]=0.f; z[2]=0.f; z[3]=0.f;
            z = __builtin_amdgcn_mfma_f32_16x16x32_bf16(q_0, kf0, z, 0, 0, 0);
            s[sub] = __builtin_amdgcn_mfma_f32_16x16x32_bf16(q_1, kf1, z, 0, 0, 0);
        }
        // p = exp(s + mask); accumulate row-sum; write P (C-layout -> [q][key])
#pragma unroll
        for (int sub = 0; sub < 4; sub++) {
            float mv = Ma[k0 + sub * 16 + lid];
#pragma unroll
            for (int r = 0; r < 4; r++) {
                float p = __expf(s[sub][r] + mv);
                u[r] += p;
                Plds[w][(qd * 4 + r) * 72 + sub * 16 + lid] = f2bfast(p);
            }
        }
        // PV as O^T = Vt * P^T (wave-local Plds round trip, no barrier)
#pragma unroll
        for (int half = 0; half < 2; half++) {
            bf16x8 pf = *(const bf16x8*)&Plds[w][lid * 72 + half * 32 + qd * 8];
#pragma unroll
            for (int ef = 0; ef < 4; ef++) {
                bf16x8 vf = *(const bf16x8*)&Vlds[(ef * 16 + lid) * 72 + half * 32 + qd * 8];
                o[ef] = __builtin_amdgcn_mfma_f32_16x16x32_bf16(vf, pf, o[ef], 0, 0, 0);
            }
        }
        if (c < 8) { ka0 = kb0; ka1 = kb1; va0 = vb0; va1 = vb1; }
    }

    // one-time row-sum reduction across key-lanes (bits 0-3)
#pragma unroll
    for (int d = 1; d <= 8; d <<= 1)
#pragma unroll
        for (int r = 0; r < 4; r++)
            u[r] += __shfl_xor(u[r], d, 64);
    if (lid == 0) {
#pragma unroll
        for (int r = 0; r < 4; r++) Lw[w][qd * 4 + r] = u[r];
    }
    float rl = 1.f / Lw[w][lid];   // l for this lane's query (wave-local ordering)

    // O write in gemm_out's swizzled A-frag order:
    // m = b*Tq + q; panel p = m>>4 (wave-uniform), rlid = lid.
    // col = h*64 + e, e = ef*16 + qd*4 + r  ->  kt = h*2 + (ef>>1),
    // cq = (ef&1)*2 + (qd>>1), j = (qd&1)*4 + r  -> one 8B store per ef.
    const size_t p = ((size_t)b * Tq + q0 + w * 16) >> 4;
#pragma unroll
    for (int ef = 0; ef < 4; ef++) {
        uint32_t w0 = pk2(o[ef][0] * rl, o[ef][1] * rl);
        uint32_t w1 = pk2(o[ef][2] * rl, o[ef][3] * rl);
        size_t chunk = ((p * 24 + h * 2 + (ef >> 1)) * 4 + (ef & 1) * 2 + (qd >> 1)) * 16 + lid;
        *(uint2*)(O + chunk * 8 + (qd & 1) * 4) = make_uint2(w0, w1);
    }
}

// ---------- launch ----------
extern "C" void kernel_launch(void* const* d_in, const int* in_sizes, int n_in,
                              void* d_out, int out_size, void* d_ws, size_t ws_size,
                              hipStream_t stream)
{
    const float* feats = (const float*)d_in[0];
    const float* inps  = (const float*)d_in[1];
    const void*  maskp = d_in[2];
    const float* W_f   = (const float*)d_in[3];
    const float* b_f   = (const float*)d_in[4];
    const float* W_i   = (const float*)d_in[5];
    const float* b_i   = (const float*)d_in[6];
    const float* Wu_v  = (const float*)d_in[7];
    const float* bu_v  = (const float*)d_in[8];
    const float* Wu_l  = (const float*)d_in[9];
    const float* bu_l  = (const float*)d_in[10];

    const size_t MAT = (size_t)DC * DC;               // 589824
    const size_t PF_E = 6ull * BB * HC * T1C * EC;
    const size_t PI_E = 6ull * BB * HC * T2C * EC;
    uint16_t* Wt  = (uint16_t*)d_ws;
    uint16_t* Osv = Wt;                               // reuses dead Wt[0..11]
    uint16_t* Osl = Wt + (size_t)BB * T1C * HC * EC;
    uint16_t* Pf  = Wt + 14 * MAT;
    uint16_t* Pi  = Pf + PF_E;
    int* flags    = (int*)(Pi + PI_E);

    // Swizzled bf16 X lives in d_out's first ~21 MB: d_out is only written by
    // the final gemm_out launch (stream-ordered after all Xs reads).
    uint16_t* Xsf = (uint16_t*)d_out;
    uint16_t* Xsi = Xsf + (size_t)BB * T1C * DC;

    prep<<<dim3(WT_BLOCKS + XS_BLOCKS + 1), dim3(256), 0, stream>>>(
        W_f, W_i, Wu_v, Wu_l, Wt, feats, inps, Xsf, Xsi,
        (const uint32_t*)maskp, flags);

    gemm_proj_mfma<<<dim3(72, 36), dim3(256), 0, stream>>>(
        Xsf, Xsi, Wt, b_f, b_i, Pf, Pi);

    attn_mfma<<<dim3(BB * HC, 9), dim3(256), 0, stream>>>(
        Pf, Pi, maskp, flags, Osv, Osl);

    gemm_out_mfma<<<dim3(72, 6), dim3(256), 0, stream>>>(
        Osv, Osl, Wt, bu_v, bu_l, (float*)d_out);
}

// Round 7
// 244.093 us; speedup vs baseline: 1.1685x; 1.0444x over previous
//
#include <hip/hip_runtime.h>
#include <stdint.h>

// Problem constants
#define BB 16
#define T1C 512
#define T2C 64
#define DC 768
#define HC 12
#define EC 64
#define SC 576          // T1+T2
#define QSCALE 0.35355339059327379f   // 64^-0.25

typedef __attribute__((ext_vector_type(8))) short bf16x8;   // 8 bf16 = 4 VGPRs
typedef __attribute__((ext_vector_type(4))) float f32x4;    // MFMA C/D

// ---------- bf16 helpers ----------
__device__ __forceinline__ uint16_t f2b(float f) {          // RNE
    union { float f; uint32_t i; } v; v.f = f;
    return (uint16_t)((v.i + 0x7fffu + ((v.i >> 16) & 1u)) >> 16);
}
__device__ __forceinline__ uint16_t f2bfast(float f) {      // round-half-up (cheap)
    union { float f; uint32_t i; } v; v.f = f;
    return (uint16_t)((v.i + 0x8000u) >> 16);
}
__device__ __forceinline__ uint32_t pk2(float a, float b) {
    return (uint32_t)f2b(a) | ((uint32_t)f2b(b) << 16);
}

// async global->LDS, 16B per lane; LDS dest = wave-uniform base + lane*16
__device__ __forceinline__ void gll16(const void* g, void* l) {
    __builtin_amdgcn_global_load_lds(
        (const __attribute__((address_space(1))) uint32_t*)(uintptr_t)g,
        (__attribute__((address_space(3))) uint32_t*)(uintptr_t)l, 16, 0, 0);
}

#define WT_BLOCKS (24 * 24 * 14)   // 8064 wtrans blocks
#define XS_BLOCKS 3456             // 884736 chunks / 256

// ---------- fused prep: wtrans + xswz + detect in ONE launch ----------
// wtrans now emits Wt[z] in CHUNK order (same frag layout as Xs):
//   chunk cc = ((p*24 + kt)*4 + qd)*16 + rlid, p = f>>4, rlid = f&15,
//   holding W_z[kt*32+qd*8 .. +7][p*16+rlid]  (i.e. f-major transposed).
// GEMM B-staging and B-frag reads then use the SAME linear conflict-free
// pattern as A (lane -> contiguous 16B), eliminating the 8-way bank
// conflict on B frag ds_reads (was all 3.98M conflict cycles).
__global__ __launch_bounds__(256) void prep(
    const float* __restrict__ Wf, const float* __restrict__ Wi,
    const float* __restrict__ Wuv, const float* __restrict__ Wul,
    uint16_t* __restrict__ Wt,
    const float* __restrict__ Xf, const float* __restrict__ Xi,
    uint16_t* __restrict__ Of, uint16_t* __restrict__ Oi,
    const uint32_t* __restrict__ mw, int* __restrict__ flags)
{
    __shared__ union { float tile[32][33]; int d[3]; } sh;
    const int bid = blockIdx.x;
    if (bid < WT_BLOCKS) {
        // ---- weight transpose + f32->bf16 -> chunk-order Wt ----
        const int z = bid / 576, r = bid % 576;
        const int kx = r % 24, fy = r / 24;      // k-tile kt = kx, f block = fy*32
        const float* src = (z < 6)  ? Wf + (size_t)z * DC * DC
                         : (z < 12) ? Wi + (size_t)(z - 6) * DC * DC
                         : (z == 12 ? Wuv : Wul);
        uint16_t* dst = Wt + (size_t)z * DC * DC;
        const int tx = threadIdx.x & 31, ty = threadIdx.x >> 5;
        const int k0 = kx * 32, f0 = fy * 32;
#pragma unroll
        for (int q = 0; q < 4; q++)
            sh.tile[ty + q * 8][tx] = src[(size_t)(k0 + ty + q * 8) * DC + f0 + tx];
        __syncthreads();
        if (threadIdx.x < 128) {
            const int fl = threadIdx.x & 31, kg = threadIdx.x >> 5;  // f lane, qd
            const int p = (f0 + fl) >> 4, rlid = fl & 15;
            uint4 o;
            o.x = pk2(sh.tile[kg * 8 + 0][fl], sh.tile[kg * 8 + 1][fl]);
            o.y = pk2(sh.tile[kg * 8 + 2][fl], sh.tile[kg * 8 + 3][fl]);
            o.z = pk2(sh.tile[kg * 8 + 4][fl], sh.tile[kg * 8 + 5][fl]);
            o.w = pk2(sh.tile[kg * 8 + 6][fl], sh.tile[kg * 8 + 7][fl]);
            *(uint4*)(dst + ((size_t)((p * 24 + kx) * 4 + kg) * 16 + rlid) * 8) = o;
        }
    } else if (bid < WT_BLOCKS + XS_BLOCKS) {
        // ---- X f32 -> bf16 swizzle (MFMA A-fragment order) ----
        const int nf = BB * T1C * DC / 8;
        const int ni = BB * T2C * DC / 8;
        int t = (bid - WT_BLOCKS) * 256 + threadIdx.x;
        const float* src; uint16_t* dst; int cc;
        if (t < nf) { src = Xf; dst = Of; cc = t; }
        else        { cc = t - nf; if (cc >= ni) return; src = Xi; dst = Oi; }
        int rlid = cc & 15;
        int t2 = cc >> 4;
        int qd = t2 & 3;
        int t3 = t2 >> 2;
        int kt = t3 % 24;
        int p  = t3 / 24;
        const float* sp = src + (size_t)(p * 16 + rlid) * DC + kt * 32 + qd * 8;
        float4 a = *(const float4*)sp;
        float4 b = *(const float4*)(sp + 4);
        uint4 o;
        o.x = pk2(a.x, a.y); o.y = pk2(a.z, a.w);
        o.z = pk2(b.x, b.y); o.w = pk2(b.z, b.w);
        *(uint4*)(dst + (size_t)cc * 8) = o;
    } else {
        // ---- mask layout detect (deterministic -> graph-safe) ----
        if (threadIdx.x == 0) { sh.d[0] = 0; sh.d[1] = 0; sh.d[2] = 0; }
        __syncthreads();
        int lW = 0, lB = 0, lL = 0;
        for (int i = threadIdx.x; i < 2304; i += 256) {
            uint32_t w = mw[i];
            if (w > 1u) lW = 1;
            if (((w) & 0xffu) > 1u || ((w >> 8) & 0xffu) > 1u ||
                ((w >> 16) & 0xffu) > 1u || ((w >> 24) & 0xffu) > 1u) lB = 1;
            if ((w & 0xffffu) > 1u) lL = 1;
        }
        if (lW) atomicOr(&sh.d[0], 1);
        if (lB) atomicOr(&sh.d[1], 1);
        if (lL) atomicOr(&sh.d[2], 1);
        __syncthreads();
        if (threadIdx.x == 0)
            flags[0] = (!sh.d[0]) ? 0 : ((!sh.d[1]) ? 1 : (sh.d[2] ? 2 : 0));
    }
}

#define BSTR 76   // epilogue bounce stride (bf16 elems), conflict-free

// ---------- MFMA projection GEMM: both operands chunk-order staged ----------
// 128x128, 4 waves, BK=32, double-buffered A+B LDS (32 KB), counted vmcnt(4).
// A and B now share the SAME chunk layout -> all stage gll16s are 1KB bursts
// and all frag ds_read_b128 are linear (lane -> 16B), zero bank conflicts.
__global__ __launch_bounds__(256, 4) void gemm_proj_mfma(
    const uint16_t* __restrict__ Xsf, const uint16_t* __restrict__ Xsi,
    const uint16_t* __restrict__ Wt,
    const float* __restrict__ b_f, const float* __restrict__ b_i,
    uint16_t* __restrict__ Pf, uint16_t* __restrict__ Pi)
{
    __shared__ union {
        struct { uint16_t A[2][128 * 32]; uint16_t B[2][128 * 32]; } st; // 32 KB
        uint16_t bounce[4][16 * BSTR];        // 9.5 KB epilogue
    } sm;
    const int tid = threadIdx.x;
    const int w = tid >> 6, l = tid & 63;
    const bool isf = (blockIdx.x < 64);
    const int mx = isf ? blockIdx.x : blockIdx.x - 64;
    const int m0 = mx * 128;
    const int T  = isf ? T1C : T2C;
    const uint16_t* Xs = isf ? Xsf : Xsi;
    const float* bias  = isf ? b_f : b_i;
    uint16_t* P        = isf ? Pf : Pi;
    const int vmask    = isf ? 0x24 : 0x22;
    const int k6 = blockIdx.y / 6, nt = blockIdx.y % 6;
    const int n0 = nt * 128;
    const uint16_t* Bsrc = Wt + (size_t)((isf ? 0 : 6) + k6) * DC * DC;

    const int lid = l & 15, qd = l >> 4;
    const int wm = w >> 1, wn = w & 1;
    const int c0 = w * 2;                     // this wave's 2 A/B panels

    f32x4 acc[4][4] = {};

    // stage tile t: A panels mx*8+c0..+1, B panels nt*8+c0..+1 (1KB bursts)
#define PJ_S(bu, t) { \
        _Pragma("unroll") for (int n = 0; n < 2; n++) \
            gll16(Xs + ((size_t)((mx * 8 + c0 + n) * 24 + (t)) * 64 + l) * 8, \
                  &sm.st.A[bu][(c0 + n) * 512]); \
        _Pragma("unroll") for (int n = 0; n < 2; n++) \
            gll16(Bsrc + ((size_t)((nt * 8 + c0 + n) * 24 + (t)) * 64 + l) * 8, \
                  &sm.st.B[bu][(c0 + n) * 512]); }
#define PJ_C(bu) { bf16x8 aq[4], bq[4]; \
        _Pragma("unroll") for (int i = 0; i < 4; i++) \
            aq[i] = *(const bf16x8*)&sm.st.A[bu][((wm * 4 + i) * 64 + l) * 8]; \
        _Pragma("unroll") for (int j = 0; j < 4; j++) \
            bq[j] = *(const bf16x8*)&sm.st.B[bu][((wn * 4 + j) * 64 + l) * 8]; \
        _Pragma("unroll") for (int i = 0; i < 4; i++) \
        _Pragma("unroll") for (int j = 0; j < 4; j++) \
            acc[i][j] = __builtin_amdgcn_mfma_f32_16x16x32_bf16(aq[i], bq[j], acc[i][j], 0, 0, 0); }

    PJ_S(0, 0);                                // prologue: tile 0 in flight (4)

    for (int kt = 0; kt < DC / 32; ++kt) {
        const int cb = kt & 1, nb = cb ^ 1;
        __builtin_amdgcn_s_barrier();          // all waves done reading buf nb
        __builtin_amdgcn_sched_barrier(0);
        if (kt < 23) {
            PJ_S(nb, kt + 1);                  // outstanding: S(t)4 + S(t+1)4
            asm volatile("s_waitcnt vmcnt(4)" ::: "memory");  // retire S(t)
        } else {
            asm volatile("s_waitcnt vmcnt(0)" ::: "memory");  // final drain
        }
        __builtin_amdgcn_sched_barrier(0);
        __builtin_amdgcn_s_barrier();          // publish tile kt cross-wave
        __builtin_amdgcn_sched_barrier(0);
        PJ_C(cb);
    }
#undef PJ_S
#undef PJ_C

    float bv[4];
#pragma unroll
    for (int j = 0; j < 4; j++)
        bv[j] = bias[k6 * DC + n0 + wn * 64 + j * 16 + lid];
    __syncthreads();   // all waves' K-loop LDS reads done before bounce overwrite

    uint16_t* reg = sm.bounce[w];
    const int mb = m0 + wm * 64;
    const int b = mb / T, tb = mb - b * T;     // 64-row wave tile never crosses b
    const int h = nt * 2 + wn;
    const int rrow = l >> 2;                   // readback row within pass
    const int rcol = (l & 3) * 16;             // readback col chunk

    if (!((vmask >> k6) & 1)) {
        // normal [t][e]: pass p = m-rows p*16..p*16+15 (i = p)
        uint16_t* dst0 = P + ((((size_t)k6 * BB + b) * HC + h) * T + tb + rrow) * EC + rcol;
#pragma unroll
        for (int p = 0; p < 4; p++) {
#pragma unroll
            for (int j = 0; j < 4; j++)
#pragma unroll
                for (int r = 0; r < 4; r++)
                    reg[(qd * 4 + r) * BSTR + j * 16 + lid] =
                        f2b((acc[p][j][r] + bv[j]) * QSCALE);
            uint4 d0 = *(const uint4*)&reg[rrow * BSTR + rcol];
            uint4 d1 = *(const uint4*)&reg[rrow * BSTR + rcol + 8];
            uint16_t* dst = dst0 + (size_t)p * 16 * EC;
            *(uint4*)dst = d0;
            *(uint4*)(dst + 8) = d1;
        }
    } else {
        // transposed [e][t]: pass p = e-rows p*16..p*16+15 (j = p)
        uint16_t* dst0 = P + (size_t)k6 * BB * HC * T * EC
                           + (((size_t)b * HC + h) * EC + rrow) * T + tb + rcol;
#pragma unroll
        for (int p = 0; p < 4; p++) {
#pragma unroll
            for (int i = 0; i < 4; i++) {
                uint32_t w0 = pk2((acc[i][p][0] + bv[p]) * QSCALE,
                                  (acc[i][p][1] + bv[p]) * QSCALE);
                uint32_t w1 = pk2((acc[i][p][2] + bv[p]) * QSCALE,
                                  (acc[i][p][3] + bv[p]) * QSCALE);
                *(uint2*)&reg[lid * BSTR + i * 16 + qd * 4] = make_uint2(w0, w1);
            }
            uint4 d0 = *(const uint4*)&reg[rrow * BSTR + rcol];
            uint4 d1 = *(const uint4*)&reg[rrow * BSTR + rcol + 8];
            uint16_t* dst = dst0 + (size_t)p * 16 * T;
            *(uint4*)dst = d0;
            *(uint4*)(dst + 8) = d1;
        }
    }
}

// ---------- MFMA output GEMM: same chunk-order both-staged schedule ----------
__global__ __launch_bounds__(256, 4) void gemm_out_mfma(
    const uint16_t* __restrict__ Osv, const uint16_t* __restrict__ Osl,
    const uint16_t* __restrict__ Wt,
    const float* __restrict__ bu_v, const float* __restrict__ bu_l,
    float* __restrict__ out)
{
    __shared__ struct { uint16_t A[2][128 * 32]; uint16_t B[2][128 * 32]; } st;
    const int tid = threadIdx.x;
    const int w = tid >> 6, l = tid & 63;
    const bool isv = (blockIdx.x < 64);
    const int mx = isv ? blockIdx.x : blockIdx.x - 64;
    const int m0 = mx * 128;
    const int rowoff = isv ? 0 : BB * T1C;
    const uint16_t* A = isv ? Osv : Osl;
    const uint16_t* Wtm = Wt + (size_t)(isv ? 12 : 13) * DC * DC;
    const float* bias = isv ? bu_v : bu_l;
    const int n0 = blockIdx.y * 128;
    const int lid = l & 15, qd = l >> 4;
    const int wm = w >> 1, wn = w & 1;
    const int c0 = w * 2;

    f32x4 acc[4][4] = {};

#define GO_S(bu, t) { \
        _Pragma("unroll") for (int n = 0; n < 2; n++) \
            gll16(A + ((size_t)((mx * 8 + c0 + n) * 24 + (t)) * 64 + l) * 8, \
                  &st.A[bu][(c0 + n) * 512]); \
        _Pragma("unroll") for (int n = 0; n < 2; n++) \
            gll16(Wtm + ((size_t)((blockIdx.y * 8 + c0 + n) * 24 + (t)) * 64 + l) * 8, \
                  &st.B[bu][(c0 + n) * 512]); }
#define GO_C(bu) { bf16x8 aq[4], bq[4]; \
        _Pragma("unroll") for (int i = 0; i < 4; i++) \
            aq[i] = *(const bf16x8*)&st.A[bu][((wm * 4 + i) * 64 + l) * 8]; \
        _Pragma("unroll") for (int j = 0; j < 4; j++) \
            bq[j] = *(const bf16x8*)&st.B[bu][((wn * 4 + j) * 64 + l) * 8]; \
        _Pragma("unroll") for (int i = 0; i < 4; i++) \
        _Pragma("unroll") for (int j = 0; j < 4; j++) \
            acc[i][j] = __builtin_amdgcn_mfma_f32_16x16x32_bf16(aq[i], bq[j], acc[i][j], 0, 0, 0); }

    GO_S(0, 0);

    for (int kt = 0; kt < DC / 32; ++kt) {
        const int cb = kt & 1, nb = cb ^ 1;
        __builtin_amdgcn_s_barrier();
        __builtin_amdgcn_sched_barrier(0);
        if (kt < 23) {
            GO_S(nb, kt + 1);
            asm volatile("s_waitcnt vmcnt(4)" ::: "memory");
        } else {
            asm volatile("s_waitcnt vmcnt(0)" ::: "memory");
        }
        __builtin_amdgcn_sched_barrier(0);
        __builtin_amdgcn_s_barrier();
        __builtin_amdgcn_sched_barrier(0);
        GO_C(cb);
    }
#undef GO_S
#undef GO_C

    float bv[4];
#pragma unroll
    for (int j = 0; j < 4; j++)
        bv[j] = bias[n0 + wn * 64 + j * 16 + lid];
#pragma unroll
    for (int i = 0; i < 4; i++)
#pragma unroll
        for (int j = 0; j < 4; j++)
#pragma unroll
            for (int r = 0; r < 4; r++) {
                int m = m0 + wm * 64 + i * 16 + qd * 4 + r;
                int f = n0 + wn * 64 + j * 16 + lid;
                out[(size_t)(rowoff + m) * DC + f] = acc[i][j][r] + bv[j];
            }
}

// ---------- MFMA flash attention: reg-prefetch double-buffered staging ----------
__global__ __launch_bounds__(256, 3) void attn_mfma(
    const uint16_t* __restrict__ Pf,
    const uint16_t* __restrict__ Pi,
    const void* __restrict__ maskp,
    const int* __restrict__ flags,
    uint16_t* __restrict__ Osv,        // swizzled visual O (M=8192)
    uint16_t* __restrict__ Osl)        // swizzled language O (M=1024)
{
    __shared__ uint16_t Klds[64 * 72];      // [key][e]
    __shared__ uint16_t Vlds[64 * 72];      // [e][key]
    __shared__ uint16_t Plds[4][16 * 72];   // per-wave P [q][key]
    __shared__ float    Ma[SC];
    __shared__ float    Lw[4][16];

    const int bh = blockIdx.x;
    const int tile = blockIdx.y;
    const int b = bh / HC, h = bh % HC;
    const int tid = threadIdx.x;
    const int w = tid >> 6, l = tid & 63;
    const int lid = l & 15, qd = l >> 4;

    const size_t SF = (size_t)BB * HC * T1C * EC;
    const size_t SI = (size_t)BB * HC * T2C * EC;

    const bool vis = (tile < 8);
    const uint16_t *Qa, *Qb, *K1, *K2, *V1, *V2;
    uint16_t* O; int Tq, q0;
    if (vis) { Qa = Pf + 1 * SF; Qb = Pf + 3 * SF; K1 = Pf;          K2 = Pi;
               V1 = Pf + 2 * SF; V2 = Pi + 1 * SI; O = Osv; Tq = T1C; q0 = tile * 64; }
    else     { Qa = Pi + 2 * SI; Qb = Pi + 3 * SI; K1 = Pf + 4 * SF; K2 = Pi + 4 * SI;
               V1 = Pf + 5 * SF; V2 = Pi + 5 * SI; O = Osl; Tq = T2C; q0 = 0; }

    {
        const int kind = flags[0];
        for (int i = tid; i < SC; i += 256) {
            int idx = b * SC + i;
            int mv;
            if (kind == 0)      mv = ((const uint32_t*)maskp)[idx] != 0u;
            else if (kind == 1) mv = ((const uint8_t*)maskp)[idx] != 0;
            else                mv = ((const uint16_t*)maskp)[idx] != 0;
            Ma[i] = mv ? -1e9f : 0.0f;
        }
    }

    // preload BOTH Q variants (the 9th chunk switches query matrix)
    const int q = q0 + w * 16 + lid;
    const uint16_t* Qrow  = Qa + ((size_t)bh * Tq + q) * EC;
    const uint16_t* Qrow2 = Qb + ((size_t)bh * Tq + q) * EC;
    bf16x8 qf0 = *(const bf16x8*)(Qrow + qd * 8);
    bf16x8 qf1 = *(const bf16x8*)(Qrow + 32 + qd * 8);
    bf16x8 qg0 = *(const bf16x8*)(Qrow2 + qd * 8);
    bf16x8 qg1 = *(const bf16x8*)(Qrow2 + 32 + qd * 8);

    f32x4 o[4];
#pragma unroll
    for (int ef = 0; ef < 4; ef++) { o[ef][0]=0.f; o[ef][1]=0.f; o[ef][2]=0.f; o[ef][3]=0.f; }
    float u[4] = {0.f, 0.f, 0.f, 0.f};

    const int skey = tid >> 2, se0 = (tid & 3) * 16;   // K stage (row, col chunk)
    const int ve = tid >> 2,  vc = tid & 3;            // V stage (e-row, key chunk)

    // chunk-c staging source addresses (c compile-time under full unroll)
    auto kptr = [&](int c) -> const uint16_t* {
        return (c < 8) ? K1 + ((size_t)bh * T1C + c * 64 + skey) * EC + se0
                       : K2 + ((size_t)bh * T2C + skey) * EC + se0;
    };
    auto vptr = [&](int c) -> const uint16_t* {
        return (c < 8) ? V1 + ((size_t)bh * EC + ve) * T1C + c * 64 + vc * 16
                       : V2 + ((size_t)bh * EC + ve) * T2C + vc * 16;
    };

    // prologue: issue chunk 0 loads into current regs
    uint4 ka0 = *(const uint4*)kptr(0);
    uint4 ka1 = *(const uint4*)(kptr(0) + 8);
    uint4 va0 = *(const uint4*)vptr(0);
    uint4 va1 = *(const uint4*)(vptr(0) + 8);

#pragma unroll
    for (int c = 0; c < 9; ++c) {
        // issue next chunk's loads FIRST (newer in vmcnt order; the compiler's
        // auto-wait before the ds_writes below then only drains chunk c's loads)
        uint4 kb0, kb1, vb0, vb1;
        if (c < 8) {
            kb0 = *(const uint4*)kptr(c + 1);
            kb1 = *(const uint4*)(kptr(c + 1) + 8);
            vb0 = *(const uint4*)vptr(c + 1);
            vb1 = *(const uint4*)(vptr(c + 1) + 8);
        }
        __builtin_amdgcn_s_barrier();              // prev chunk LDS reads done
        __builtin_amdgcn_sched_barrier(0);
        *(uint4*)&Klds[skey * 72 + se0]         = ka0;
        *(uint4*)&Klds[skey * 72 + se0 + 8]     = ka1;
        *(uint4*)&Vlds[ve * 72 + vc * 16]       = va0;
        *(uint4*)&Vlds[ve * 72 + vc * 16 + 8]   = va1;
        asm volatile("s_waitcnt lgkmcnt(0)" ::: "memory");
        __builtin_amdgcn_sched_barrier(0);
        __builtin_amdgcn_s_barrier();              // publish K/V (and Ma @c=0)
        __builtin_amdgcn_sched_barrier(0);

        const int k0 = c * 64;
        const bf16x8 q_0 = (c < 8) ? qf0 : qg0;
        const bf16x8 q_1 = (c < 8) ? qf1 : qg1;
        // QK^T: D[q][key]
        f32x4 s[4];
#pragma unroll
        for (int sub = 0; sub < 4; sub++) {
            bf16x8 kf0 = *(const bf16x8*)&Klds[(sub * 16 + lid) * 72 + qd * 8];
            bf16x8 kf1 = *(const bf16x8*)&Klds[(sub * 16 + lid) * 72 + 32 + qd * 8];
            f32x4 z; z[0]=0.f; z[1]=0.f; z[2]=0.f; z[3]=0.f;
            z = __builtin_amdgcn_mfma_f32_16x16x32_bf16(q_0, kf0, z, 0, 0, 0);
            s[sub] = __builtin_amdgcn_mfma_f32_16x16x32_bf16(q_1, kf1, z, 0, 0, 0);
        }
        // p = exp(s + mask); accumulate row-sum; write P (C-layout -> [q][key])
#pragma unroll
        for (int sub = 0; sub < 4; sub++) {
            float mv = Ma[k0 + sub * 16 + lid];
#pragma unroll
            for (int r = 0; r < 4; r++) {
                float p = __expf(s[sub][r] + mv);
                u[r] += p;
                Plds[w][(qd * 4 + r) * 72 + sub * 16 + lid] = f2bfast(p);
            }
        }
        // PV as O^T = Vt * P^T (wave-local Plds round trip, no barrier)
#pragma unroll
        for (int half = 0; half < 2; half++) {
            bf16x8 pf = *(const bf16x8*)&Plds[w][lid * 72 + half * 32 + qd * 8];
#pragma unroll
            for (int ef = 0; ef < 4; ef++) {
                bf16x8 vf = *(const bf16x8*)&Vlds[(ef * 16 + lid) * 72 + half * 32 + qd * 8];
                o[ef] = __builtin_amdgcn_mfma_f32_16x16x32_bf16(vf, pf, o[ef], 0, 0, 0);
            }
        }
        if (c < 8) { ka0 = kb0; ka1 = kb1; va0 = vb0; va1 = vb1; }
    }

    // one-time row-sum reduction across key-lanes (bits 0-3)
#pragma unroll
    for (int d = 1; d <= 8; d <<= 1)
#pragma unroll
        for (int r = 0; r < 4; r++)
            u[r] += __shfl_xor(u[r], d, 64);
    if (lid == 0) {
#pragma unroll
        for (int r = 0; r < 4; r++) Lw[w][qd * 4 + r] = u[r];
    }
    float rl = 1.f / Lw[w][lid];   // l for this lane's query (wave-local ordering)

    // O write in gemm_out's swizzled A-frag order:
    // m = b*Tq + q; panel p = m>>4 (wave-uniform), rlid = lid.
    // col = h*64 + e, e = ef*16 + qd*4 + r  ->  kt = h*2 + (ef>>1),
    // cq = (ef&1)*2 + (qd>>1), j = (qd&1)*4 + r  -> one 8B store per ef.
    const size_t p = ((size_t)b * Tq + q0 + w * 16) >> 4;
#pragma unroll
    for (int ef = 0; ef < 4; ef++) {
        uint32_t w0 = pk2(o[ef][0] * rl, o[ef][1] * rl);
        uint32_t w1 = pk2(o[ef][2] * rl, o[ef][3] * rl);
        size_t chunk = ((p * 24 + h * 2 + (ef >> 1)) * 4 + (ef & 1) * 2 + (qd >> 1)) * 16 + lid;
        *(uint2*)(O + chunk * 8 + (qd & 1) * 4) = make_uint2(w0, w1);
    }
}

// ---------- launch ----------
extern "C" void kernel_launch(void* const* d_in, const int* in_sizes, int n_in,
                              void* d_out, int out_size, void* d_ws, size_t ws_size,
                              hipStream_t stream)
{
    const float* feats = (const float*)d_in[0];
    const float* inps  = (const float*)d_in[1];
    const void*  maskp = d_in[2];
    const float* W_f   = (const float*)d_in[3];
    const float* b_f   = (const float*)d_in[4];
    const float* W_i   = (const float*)d_in[5];
    const float* b_i   = (const float*)d_in[6];
    const float* Wu_v  = (const float*)d_in[7];
    const float* bu_v  = (const float*)d_in[8];
    const float* Wu_l  = (const float*)d_in[9];
    const float* bu_l  = (const float*)d_in[10];

    const size_t MAT = (size_t)DC * DC;               // 589824
    const size_t PF_E = 6ull * BB * HC * T1C * EC;
    const size_t PI_E = 6ull * BB * HC * T2C * EC;
    uint16_t* Wt  = (uint16_t*)d_ws;
    uint16_t* Osv = Wt;                               // reuses dead Wt[0..11]
    uint16_t* Osl = Wt + (size_t)BB * T1C * HC * EC;
    uint16_t* Pf  = Wt + 14 * MAT;
    uint16_t* Pi  = Pf + PF_E;
    int* flags    = (int*)(Pi + PI_E);

    // Swizzled bf16 X lives in d_out's first ~21 MB: d_out is only written by
    // the final gemm_out launch (stream-ordered after all Xs reads).
    uint16_t* Xsf = (uint16_t*)d_out;
    uint16_t* Xsi = Xsf + (size_t)BB * T1C * DC;

    prep<<<dim3(WT_BLOCKS + XS_BLOCKS + 1), dim3(256), 0, stream>>>(
        W_f, W_i, Wu_v, Wu_l, Wt, feats, inps, Xsf, Xsi,
        (const uint32_t*)maskp, flags);

    gemm_proj_mfma<<<dim3(72, 36), dim3(256), 0, stream>>>(
        Xsf, Xsi, Wt, b_f, b_i, Pf, Pi);

    attn_mfma<<<dim3(BB * HC, 9), dim3(256), 0, stream>>>(
        Pf, Pi, maskp, flags, Osv, Osl);

    gemm_out_mfma<<<dim3(72, 6), dim3(256), 0, stream>>>(
        Osv, Osl, Wt, bu_v, bu_l, (float*)d_out);
}